// Round 9
// baseline (1498.240 us; speedup 1.0000x reference)
//
#include <hip/hip_runtime.h>
#include <cstddef>
#include <cstdint>

// ---------------------------------------------------------------- constants
constexpr int NB   = 8;
constexpr int SEQ  = 1024;
constexpr int DIM  = 512;
constexpr int NL   = 6;
constexpr int NH   = 8;
constexpr int HDIM = 64;
constexpr int ROWS = NB * SEQ;               // 8192
constexpr size_t BSD = (size_t)ROWS * DIM;   // 4,194,304
constexpr int KHAT = 1024;                   // concat K dim

typedef __attribute__((ext_vector_type(8))) short bfrag;   // 8 bf16 = 16B
typedef __attribute__((ext_vector_type(4))) float f32x4;
typedef __attribute__((ext_vector_type(4))) unsigned short us4;

__device__ __forceinline__ void f4a(const float4 v, float* a) {
    a[0] = v.x; a[1] = v.y; a[2] = v.z; a[3] = v.w;
}
__device__ __forceinline__ float4 a4f(const float* a) {
    float4 v; v.x = a[0]; v.y = a[1]; v.z = a[2]; v.w = a[3]; return v;
}
__device__ __forceinline__ unsigned short f2bf(float f) {
    union { float f; uint32_t u; } x{f};
    return (unsigned short)((x.u + 0x7fffu + ((x.u >> 16) & 1u)) >> 16);
}
__device__ __forceinline__ float bf2f(unsigned short u) {
    union { uint32_t u; float f; } x;
    x.u = (uint32_t)u << 16;
    return x.f;
}
__device__ __forceinline__ uint32_t cvtpk(float lo, float hi) {
    uint32_t r;
    asm("v_cvt_pk_bf16_f32 %0, %1, %2" : "=v"(r) : "v"(lo), "v"(hi));
    return r;
}
// async global->LDS DMA, 16B per lane; LDS dest = wave-uniform base + lane*16
__device__ __forceinline__ void gload16(const unsigned short* g, void* l) {
    __builtin_amdgcn_global_load_lds(
        (const __attribute__((address_space(1))) void*)g,
        (__attribute__((address_space(3))) void*)l, 16, 0, 0);
}

constexpr float ATT_SC = 0.125f * 1.44269504f;   // hd^-0.5 * log2(e), folded into Q

// ---------------------------------------------------------------- weight prep
struct PrepArgs {
    const float* Wr[6]; const float* Wi[6];
    const float* br[6]; const float* bi[6];
};

__global__ __launch_bounds__(256)
void prep_kernel(PrepArgs a, unsigned short* __restrict__ Ball,
                 float* __restrict__ biasall, int layer)
{
    const int lin = blockIdx.y;
    const int nh_ = blockIdx.x;           // ň
    const float* Wr = a.Wr[lin] + (size_t)layer * DIM * DIM;
    const float* Wi = a.Wi[lin] + (size_t)layer * DIM * DIM;

    bool real; int n0;
    if (lin < 3) { const int dh = nh_ & 127; real = dh < 64; n0 = (nh_ >> 7) * 64 + (dh & 63); }
    else         { real = nh_ < 512; n0 = nh_ & 511; }

    const int t = threadIdx.x;
    const int kk = (t * 4) & 511;
    const bool fh = t < 128;
    const float* src;
    float sgn = 1.f;
    if (fh) src = real ? Wr : Wi;
    else { if (real) { src = Wi; sgn = -1.f; } else src = Wr; }

    float v[4];
    f4a(*(const float4*)(src + (size_t)n0 * 512 + kk), v);
    us4 o;
    #pragma unroll
    for (int j = 0; j < 4; ++j) o[j] = f2bf(sgn * v[j]);
    *(us4*)(Ball + (size_t)lin * KHAT * KHAT + (size_t)nh_ * KHAT + t * 4) = o;
    if (t == 0)
        biasall[lin * KHAT + nh_] = real ? a.br[lin][layer * DIM + n0]
                                         : a.bi[lin][layer * DIM + n0];
}

// ---------------------------------------------------------------- fused QKV GEMM
//  One launch, N=3072 (Q|K|V). 128x128 tiles; 2 K-steps of 32 per barrier
//  pair via doubled LDS buffers. Q pre-scaled by ATT_SC; V̂t key-κ-permuted.
__global__ __launch_bounds__(256)
void gemm_qkv(const unsigned short* __restrict__ Xh,
              const unsigned short* __restrict__ Ball,
              const float* __restrict__ biasall,
              unsigned short* __restrict__ Qh,
              unsigned short* __restrict__ Kh,
              unsigned short* __restrict__ Vth)
{
    __shared__ __align__(16) unsigned short Asm[2][128 * 32];
    __shared__ __align__(16) unsigned short Bsm[2][128 * 32];

    const int t = threadIdx.x, lane = t & 63, w = t >> 6;
    const int wm = w >> 1, wn = w & 1;
    const int c = lane & 15, g = lane >> 4;

    int bid = blockIdx.y * 24 + blockIdx.x;
    bid = (bid & 7) * 192 + (bid >> 3);
    const int nblk = bid % 24, mblk = bid / 24;
    const int n0g = nblk * 128;          // 0..3071
    const int m0 = mblk * 128;
    const int lin = n0g >> 10;           // 0=Q 1=K 2=V
    const int n0 = n0g & 1023;
    const unsigned short* Bh = Ball + (size_t)lin * KHAT * KHAT;
    const float* bias = biasall + lin * KHAT;

    f32x4 acc[4][4];
    #pragma unroll
    for (int i = 0; i < 4; ++i)
        #pragma unroll
        for (int j = 0; j < 4; ++j) acc[i][j] = (f32x4){0.f, 0.f, 0.f, 0.f};

    const int srow = (w << 4) + (lane >> 2);
    const int scol = (lane & 3) * 8;
    const unsigned short* gA0 = Xh + (size_t)(m0 + srow) * KHAT + scol;
    const unsigned short* gA1 = Xh + (size_t)(m0 + 64 + srow) * KHAT + scol;
    const unsigned short* gB0 = Bh + (size_t)(n0 + srow) * KHAT + scol;
    const unsigned short* gB1 = Bh + (size_t)(n0 + 64 + srow) * KHAT + scol;
    char* aB0 = (char*)Asm[0] + (w << 10);
    char* aB1 = (char*)Asm[1] + (w << 10);
    char* bB0 = (char*)Bsm[0] + (w << 10);
    char* bB1 = (char*)Bsm[1] + (w << 10);

    for (int ks = 0; ks < 16; ++ks) {
        const int k0 = ks * 64;
        __syncthreads();
        gload16(gA0 + k0, aB0);
        gload16(gA1 + k0, aB0 + 4096);
        gload16(gB0 + k0, bB0);
        gload16(gB1 + k0, bB0 + 4096);
        gload16(gA0 + k0 + 32, aB1);
        gload16(gA1 + k0 + 32, aB1 + 4096);
        gload16(gB0 + k0 + 32, bB1);
        gload16(gB1 + k0 + 32, bB1 + 4096);
        __syncthreads();

        #pragma unroll
        for (int h = 0; h < 2; ++h) {
            bfrag af[4], bf2[4];
            #pragma unroll
            for (int mi = 0; mi < 4; ++mi)
                af[mi] = *(const bfrag*)(Asm[h] + (wm * 64 + mi * 16 + c) * 32 + g * 8);
            #pragma unroll
            for (int ni = 0; ni < 4; ++ni)
                bf2[ni] = *(const bfrag*)(Bsm[h] + (wn * 64 + ni * 16 + c) * 32 + g * 8);
            #pragma unroll
            for (int mi = 0; mi < 4; ++mi)
                #pragma unroll
                for (int ni = 0; ni < 4; ++ni)
                    acc[mi][ni] = __builtin_amdgcn_mfma_f32_16x16x32_bf16(
                        af[mi], bf2[ni], acc[mi][ni], 0, 0, 0);
        }
    }

    const int mbase = m0 + wm * 64;
    const int nbase = n0 + wn * 64;
    unsigned short* dqk = (lin == 0) ? Qh : Kh;
    #pragma unroll
    for (int mi = 0; mi < 4; ++mi) {
        #pragma unroll
        for (int ni = 0; ni < 4; ++ni) {
            const int n = nbase + ni * 16 + c;
            const float bv = bias[n];
            float v[4];
            #pragma unroll
            for (int r = 0; r < 4; ++r) {
                v[r] = acc[mi][ni][r] + bv;
                if (lin == 0) v[r] *= ATT_SC;   // fold softmax scale into Q
            }
            const int mrow = mbase + mi * 16 + g * 4;
            const int b = mrow >> 10, s = mrow & 1023;
            const int h = n >> 7, dh = n & 127;
            if (lin < 2) {
                const size_t a = ((size_t)(b * NH + h) * SEQ + s) * 128 + dh;
                #pragma unroll
                for (int r = 0; r < 4; ++r) dqk[a + (size_t)r * 128] = f2bf(v[r]);
            } else {
                // κ-permute: 4-key chunk ck within its 32-block -> slot (ck&3)<<1 | ck>>2
                const int ck = (s & 31) >> 2;
                const int sp = (s & ~31) | ((((ck & 3) << 1) | (ck >> 2)) << 2);
                const size_t a = ((size_t)(b * NH + h) * 128 + dh) * SEQ + sp;
                us4 o;
                #pragma unroll
                for (int r = 0; r < 4; ++r) o[r] = f2bf(v[r]);
                *(us4*)(Vth + a) = o;
            }
        }
    }
}

// ---------------------------------------------------------------- MFMA GEMM (bf16 out)
//  2 K-steps per barrier pair, doubled LDS buffers.
template <bool RELU>
__global__ __launch_bounds__(256)
void gemm_mfma(const unsigned short* __restrict__ Xh,
               const unsigned short* __restrict__ Bh,
               const float* __restrict__ bias,
               unsigned short* __restrict__ Yh)
{
    __shared__ __align__(16) unsigned short Asm[2][128 * 32];
    __shared__ __align__(16) unsigned short Bsm[2][128 * 32];

    const int t = threadIdx.x, lane = t & 63, w = t >> 6;
    const int wm = w >> 1, wn = w & 1;
    const int c = lane & 15, g = lane >> 4;

    int bid = blockIdx.y * 8 + blockIdx.x;
    bid = (bid & 7) * 64 + (bid >> 3);
    const int n0 = (bid & 7) * 128;
    const int m0 = (bid >> 3) * 128;

    f32x4 acc[4][4];
    #pragma unroll
    for (int i = 0; i < 4; ++i)
        #pragma unroll
        for (int j = 0; j < 4; ++j) acc[i][j] = (f32x4){0.f, 0.f, 0.f, 0.f};

    const int srow = (w << 4) + (lane >> 2);
    const int scol = (lane & 3) * 8;
    const unsigned short* gA0 = Xh + (size_t)(m0 + srow) * KHAT + scol;
    const unsigned short* gA1 = Xh + (size_t)(m0 + 64 + srow) * KHAT + scol;
    const unsigned short* gB0 = Bh + (size_t)(n0 + srow) * KHAT + scol;
    const unsigned short* gB1 = Bh + (size_t)(n0 + 64 + srow) * KHAT + scol;
    char* aB0 = (char*)Asm[0] + (w << 10);
    char* aB1 = (char*)Asm[1] + (w << 10);
    char* bB0 = (char*)Bsm[0] + (w << 10);
    char* bB1 = (char*)Bsm[1] + (w << 10);

    for (int ks = 0; ks < 16; ++ks) {
        const int k0 = ks * 64;
        __syncthreads();
        gload16(gA0 + k0, aB0);
        gload16(gA1 + k0, aB0 + 4096);
        gload16(gB0 + k0, bB0);
        gload16(gB1 + k0, bB0 + 4096);
        gload16(gA0 + k0 + 32, aB1);
        gload16(gA1 + k0 + 32, aB1 + 4096);
        gload16(gB0 + k0 + 32, bB1);
        gload16(gB1 + k0 + 32, bB1 + 4096);
        __syncthreads();

        #pragma unroll
        for (int h = 0; h < 2; ++h) {
            bfrag af[4], bf2[4];
            #pragma unroll
            for (int mi = 0; mi < 4; ++mi)
                af[mi] = *(const bfrag*)(Asm[h] + (wm * 64 + mi * 16 + c) * 32 + g * 8);
            #pragma unroll
            for (int ni = 0; ni < 4; ++ni)
                bf2[ni] = *(const bfrag*)(Bsm[h] + (wn * 64 + ni * 16 + c) * 32 + g * 8);
            #pragma unroll
            for (int mi = 0; mi < 4; ++mi)
                #pragma unroll
                for (int ni = 0; ni < 4; ++ni)
                    acc[mi][ni] = __builtin_amdgcn_mfma_f32_16x16x32_bf16(
                        af[mi], bf2[ni], acc[mi][ni], 0, 0, 0);
        }
    }

    const int mbase = m0 + wm * 64;
    const int nbase = n0 + wn * 64;
    #pragma unroll
    for (int mi = 0; mi < 4; ++mi) {
        #pragma unroll
        for (int ni = 0; ni < 4; ++ni) {
            const int n = nbase + ni * 16 + c;
            const float bv = bias[n];
            const int mrow = mbase + mi * 16 + g * 4;
            #pragma unroll
            for (int r = 0; r < 4; ++r) {
                float v = acc[mi][ni][r] + bv;
                if (RELU) v = fmaxf(v, 0.f);
                Yh[(size_t)(mrow + r) * KHAT + n] = f2bf(v);
            }
        }
    }
}

// ---------------------------------------------------------------- MFMA flash attention
//  q-doubled: 4 waves x 32 q (QBLK=128), 512 blocks. K/V frags reused across
//  both q-groups -> 2x MFMA per LDS read. K+V in LDS (XOR-swizzled), swapped
//  QK^T, lane-local softmax, P in registers, κ-permuted V, defer-max, T14, T5.
__global__ __launch_bounds__(256)
void attn_mfma(const unsigned short* __restrict__ Qh,
               const unsigned short* __restrict__ Kh,
               const unsigned short* __restrict__ Vth,
               unsigned short* __restrict__ Ah)
{
    __shared__ __align__(16) char smem[32768];
    char* Ksm = smem;            // [64 key][128 d] bf16, XOR-swizzled, 16KB
    char* Vsm = smem + 16384;    // [128 d][64 slot] bf16, XOR-swizzled, 16KB
    const int t    = threadIdx.x;
    const int lane = t & 63;
    const int wv   = t >> 6;
    const int c    = lane & 15;
    const int g    = lane >> 4;

    // 512 blocks; XCD chunk = 64 = 8 (b,h) pairs -> K/V fills one L2
    int bid = blockIdx.x + 8 * blockIdx.y + 64 * blockIdx.z;
    bid = (bid & 7) * 64 + (bid >> 3);
    const int q0 = (bid & 7) * 128;
    const int bh = bid >> 3;
    const int hh = bh & 7, bb = bh >> 3;
    const size_t qkb = (size_t)bh * SEQ * 128;
    const size_t vtb = (size_t)bh * 128 * SEQ;

    constexpr float THR = 11.0f;   // defer threshold (log2 units)

    bfrag qf[2][4];   // two q-groups of 16 rows each (B-operand), pre-scaled
    #pragma unroll
    for (int u = 0; u < 2; ++u) {
        const unsigned short* qp = Qh + qkb + (size_t)(q0 + wv * 32 + u * 16 + c) * 128 + g * 8;
        #pragma unroll
        for (int ks = 0; ks < 4; ++ks) qf[u][ks] = *(const bfrag*)(qp + ks * 32);
    }

    f32x4 oacc[2][8];
    #pragma unroll
    for (int u = 0; u < 2; ++u)
        #pragma unroll
        for (int i = 0; i < 8; ++i) oacc[u][i] = (f32x4){0.f, 0.f, 0.f, 0.f};
    float mrun[2] = {-1e30f, -1e30f}, lrun[2] = {0.f, 0.f};

    const int kkey = t >> 2, kq = t & 3;
    const unsigned short* kgp = Kh + qkb + (size_t)kkey * 128 + kq * 32;
    const int vd = t >> 1, vh2 = t & 1;
    const unsigned short* vgp = Vth + vtb + (size_t)vd * SEQ + vh2 * 32;

    bfrag krg[4], vrg[4];
    #pragma unroll
    for (int j = 0; j < 4; ++j) krg[j] = *(const bfrag*)(kgp + j * 8);
    #pragma unroll
    for (int j = 0; j < 4; ++j) vrg[j] = *(const bfrag*)(vgp + j * 8);

    for (int k0 = 0; k0 < SEQ; k0 += 64) {
        __syncthreads();   // prior-iter LDS reads done
        #pragma unroll
        for (int j = 0; j < 4; ++j) {
            const int boff = (kkey * 256 + (kq * 32 + j * 8) * 2) ^ ((kkey & 7) << 4);
            *(bfrag*)(Ksm + boff) = krg[j];
        }
        #pragma unroll
        for (int j = 0; j < 4; ++j) {
            const int boff = (vd * 128 + (vh2 * 32 + j * 8) * 2) ^ ((vd & 7) << 4);
            *(bfrag*)(Vsm + boff) = vrg[j];
        }
        __syncthreads();

        if (k0 + 64 < SEQ) {   // T14: next-tile loads hide under compute
            const int kn = k0 + 64;
            #pragma unroll
            for (int j = 0; j < 4; ++j) krg[j] = *(const bfrag*)(kgp + (size_t)kn * 128 + j * 8);
            #pragma unroll
            for (int j = 0; j < 4; ++j) vrg[j] = *(const bfrag*)(vgp + kn + j * 8);
        }

        // ---- S^T = K̂ · Q̂ᵀ : K frags shared across both q-groups
        f32x4 sa[2][4];
        #pragma unroll
        for (int u = 0; u < 2; ++u)
            #pragma unroll
            for (int nt = 0; nt < 4; ++nt) sa[u][nt] = (f32x4){0.f, 0.f, 0.f, 0.f};
        __builtin_amdgcn_s_setprio(1);
        #pragma unroll
        for (int nt = 0; nt < 4; ++nt) {
            const int key = nt * 16 + c;
            bfrag kf[4];
            #pragma unroll
            for (int ks = 0; ks < 4; ++ks) {
                const int boff = (key * 256 + (ks * 32 + g * 8) * 2) ^ ((key & 7) << 4);
                kf[ks] = *(const bfrag*)(Ksm + boff);
            }
            #pragma unroll
            for (int u = 0; u < 2; ++u)
                #pragma unroll
                for (int ks = 0; ks < 4; ++ks)
                    sa[u][nt] = __builtin_amdgcn_mfma_f32_16x16x32_bf16(kf[ks], qf[u][ks], sa[u][nt], 0, 0, 0);
        }
        __builtin_amdgcn_s_setprio(0);

        // ---- lane-local softmax per q-group; pack P for both groups
        uint32_t pk0[2][4], pk1[2][4];
        #pragma unroll
        for (int u = 0; u < 2; ++u) {
            float mloc = sa[u][0][0];
            #pragma unroll
            for (int nt = 0; nt < 4; ++nt)
                #pragma unroll
                for (int r = 0; r < 4; ++r) mloc = fmaxf(mloc, sa[u][nt][r]);
            if (__any(mloc > mrun[u] + THR)) {
                float mt = mloc;
                mt = fmaxf(mt, __shfl_xor(mt, 16, 64));
                mt = fmaxf(mt, __shfl_xor(mt, 32, 64));
                const float mn = fmaxf(mrun[u], mt);
                const float fs = exp2f(mrun[u] - mn);
                mrun[u] = mn;
                lrun[u] *= fs;
                #pragma unroll
                for (int i = 0; i < 8; ++i) {
                    oacc[u][i][0] *= fs; oacc[u][i][1] *= fs;
                    oacc[u][i][2] *= fs; oacc[u][i][3] *= fs;
                }
            }
            float ps = 0.f;
            #pragma unroll
            for (int nt = 0; nt < 4; ++nt) {
                float p0 = exp2f(sa[u][nt][0] - mrun[u]);
                float p1 = exp2f(sa[u][nt][1] - mrun[u]);
                float p2 = exp2f(sa[u][nt][2] - mrun[u]);
                float p3 = exp2f(sa[u][nt][3] - mrun[u]);
                ps += (p0 + p1) + (p2 + p3);
                pk0[u][nt] = cvtpk(p0, p1);
                pk1[u][nt] = cvtpk(p2, p3);
            }
            ps += __shfl_xor(ps, 16, 64);
            ps += __shfl_xor(ps, 32, 64);
            lrun[u] += ps;
        }

        // ---- Oᵀ += V̂ᵀ · Pᵀ : V frags shared across both q-groups
        __builtin_amdgcn_s_setprio(1);
        #pragma unroll
        for (int k2 = 0; k2 < 2; ++k2) {
            union { uint32_t u[4]; bfrag f; } pb0, pb1;
            pb0.u[0] = pk0[0][2 * k2]; pb0.u[1] = pk1[0][2 * k2];
            pb0.u[2] = pk0[0][2 * k2 + 1]; pb0.u[3] = pk1[0][2 * k2 + 1];
            pb1.u[0] = pk0[1][2 * k2]; pb1.u[1] = pk1[1][2 * k2];
            pb1.u[2] = pk0[1][2 * k2 + 1]; pb1.u[3] = pk1[1][2 * k2 + 1];
            const int kb2 = (k2 * 32 + g * 8) * 2;
            #pragma unroll
            for (int mtl = 0; mtl < 8; ++mtl) {
                const int d = mtl * 16 + c;
                const bfrag va = *(const bfrag*)(Vsm + ((d * 128 + kb2) ^ ((d & 7) << 4)));
                oacc[0][mtl] = __builtin_amdgcn_mfma_f32_16x16x32_bf16(va, pb0.f, oacc[0][mtl], 0, 0, 0);
                oacc[1][mtl] = __builtin_amdgcn_mfma_f32_16x16x32_bf16(va, pb1.f, oacc[1][mtl], 0, 0, 0);
            }
        }
        __builtin_amdgcn_s_setprio(0);
    }

    // normalize
    #pragma unroll
    for (int u = 0; u < 2; ++u) {
        const float ic = 1.0f / lrun[u];
        #pragma unroll
        for (int i = 0; i < 8; ++i) {
            oacc[u][i][0] *= ic; oacc[u][i][1] *= ic;
            oacc[u][i][2] *= ic; oacc[u][i][3] *= ic;
        }
    }
    __syncthreads();   // done with K/V LDS; reuse as transpose scratch
    float* Ox = (float*)(smem + wv * 8192);   // per-wave [128 d][16 q]
    const int q = lane >> 2, qt = lane & 3;
    const int colbase = (qt >> 1) * 512 + hh * 64 + (qt & 1) * 32;
    #pragma unroll
    for (int u = 0; u < 2; ++u) {
        #pragma unroll
        for (int mtl = 0; mtl < 8; ++mtl)
            #pragma unroll
            for (int r = 0; r < 4; ++r)
                Ox[(mtl * 16 + 4 * g + r) * 16 + c] = oacc[u][mtl][r];
        asm volatile("s_waitcnt lgkmcnt(0)" ::: "memory");
        __builtin_amdgcn_sched_barrier(0);

        const size_t rowm = (size_t)bb * SEQ + q0 + wv * 32 + u * 16 + q;
        unsigned short* dst = Ah + rowm * KHAT + colbase;
        #pragma unroll
        for (int j = 0; j < 8; ++j) {
            us4 o;
            #pragma unroll
            for (int e = 0; e < 4; ++e) o[e] = f2bf(Ox[(qt * 32 + j * 4 + e) * 16 + q]);
            *(us4*)(dst + j * 4) = o;
        }
        asm volatile("s_waitcnt lgkmcnt(0)" ::: "memory");   // drain before next-u overwrite
        __builtin_amdgcn_sched_barrier(0);
    }
}

// ---------------------------------------------------------------- complex LayerNorm
__global__ __launch_bounds__(256)
void cln_kernel(const unsigned short* __restrict__ U,
                float* __restrict__ Xr, float* __restrict__ Xi,
                unsigned short* __restrict__ Xh,
                const float* __restrict__ Grr, const float* __restrict__ Gri,
                const float* __restrict__ Gii, const float* __restrict__ Bbr,
                const float* __restrict__ Bbi)
{
    const int lane = threadIdx.x & 63;
    const int row  = blockIdx.x * 4 + (threadIdx.x >> 6);
    const size_t off = (size_t)row * DIM;
    const int c0 = lane * 4;
    const int c1 = 256 + lane * 4;

    float xr[8], xi[8];
    {
        const unsigned short* up = U + (size_t)row * KHAT;
        us4 a0 = *(const us4*)(up + c0);
        us4 a1 = *(const us4*)(up + c1);
        us4 b0 = *(const us4*)(up + 512 + c0);
        us4 b1 = *(const us4*)(up + 512 + c1);
        float t0[4], t1[4];
        f4a(*(const float4*)&Xr[off + c0], t0);
        f4a(*(const float4*)&Xr[off + c1], t1);
        #pragma unroll
        for (int j = 0; j < 4; ++j) { xr[j] = bf2f(a0[j]) + t0[j]; xr[4 + j] = bf2f(a1[j]) + t1[j]; }
        f4a(*(const float4*)&Xi[off + c0], t0);
        f4a(*(const float4*)&Xi[off + c1], t1);
        #pragma unroll
        for (int j = 0; j < 4; ++j) { xi[j] = bf2f(b0[j]) + t0[j]; xi[4 + j] = bf2f(b1[j]) + t1[j]; }
    }

    float sr = 0.f, si = 0.f, srr = 0.f, sii = 0.f, sri = 0.f;
    #pragma unroll
    for (int j = 0; j < 8; ++j) {
        sr += xr[j]; si += xi[j];
        srr = fmaf(xr[j], xr[j], srr);
        sii = fmaf(xi[j], xi[j], sii);
        sri = fmaf(xr[j], xi[j], sri);
    }
    #pragma unroll
    for (int m = 32; m >= 1; m >>= 1) {
        sr  += __shfl_xor(sr,  m, 64);
        si  += __shfl_xor(si,  m, 64);
        srr += __shfl_xor(srr, m, 64);
        sii += __shfl_xor(sii, m, 64);
        sri += __shfl_xor(sri, m, 64);
    }

    const float inv_d = 1.0f / DIM;
    const float mr = sr * inv_d, mi = si * inv_d;
    const float Vrr = srr * inv_d - mr * mr + 1e-5f;
    const float Vii = sii * inv_d - mi * mi + 1e-5f;
    const float Vri = sri * inv_d - mr * mi;
    const float s  = sqrtf(Vrr * Vii - Vri * Vri);
    const float tt = sqrtf(Vrr + Vii + 2.0f * s);
    const float ist = 1.0f / (s * tt);
    const float Wrr = (Vii + s) * ist;
    const float Wii = (Vrr + s) * ist;
    const float Wri = -Vri * ist;

    #pragma unroll
    for (int half = 0; half < 2; ++half) {
        const int c = half ? c1 : c0;
        float grr[4], gri[4], gii[4], pbr[4], pbi[4];
        f4a(*(const float4*)&Grr[c], grr);
        f4a(*(const float4*)&Gri[c], gri);
        f4a(*(const float4*)&Gii[c], gii);
        f4a(*(const float4*)&Bbr[c], pbr);
        f4a(*(const float4*)&Bbi[c], pbi);
        float outr[4], outi[4];
        #pragma unroll
        for (int j = 0; j < 4; ++j) {
            const int idx = half * 4 + j;
            const float cr = xr[idx] - mr;
            const float ci = xi[idx] - mi;
            const float hr = Wrr * cr + Wri * ci;
            const float hi = Wri * cr + Wii * ci;
            outr[j] = fmaf(grr[j], hr, fmaf(gri[j], hi, pbr[j]));
            outi[j] = fmaf(gri[j], hr, fmaf(gii[j], hi, pbi[j]));
        }
        *(float4*)&Xr[off + c] = a4f(outr);
        *(float4*)&Xi[off + c] = a4f(outi);
        us4 hr_, hi_;
        #pragma unroll
        for (int j = 0; j < 4; ++j) { hr_[j] = f2bf(outr[j]); hi_[j] = f2bf(outi[j]); }
        *(us4*)(Xh + (size_t)row * KHAT + c)       = hr_;
        *(us4*)(Xh + (size_t)row * KHAT + 512 + c) = hi_;
    }
}

// ---------------------------------------------------------------- init: copy + bf16 X̂
__global__ __launch_bounds__(256)
void init_cvt(const float* __restrict__ xr, const float* __restrict__ xi,
              float* __restrict__ outr, float* __restrict__ outi,
              unsigned short* __restrict__ Xh)
{
    const size_t i = ((size_t)blockIdx.x * 256 + threadIdx.x) * 4;
    float vr[4], vi[4];
    f4a(*(const float4*)(xr + i), vr);
    f4a(*(const float4*)(xi + i), vi);
    *(float4*)(outr + i) = a4f(vr);
    *(float4*)(outi + i) = a4f(vi);
    const size_t m = i >> 9;
    const int k = (int)(i & 511);
    us4 a, b;
    #pragma unroll
    for (int j = 0; j < 4; ++j) { a[j] = f2bf(vr[j]); b[j] = f2bf(vi[j]); }
    *(us4*)(Xh + m * KHAT + k)       = a;
    *(us4*)(Xh + m * KHAT + 512 + k) = b;
}

// ---------------------------------------------------------------- host
extern "C" void kernel_launch(void* const* d_in, const int* in_sizes, int n_in,
                              void* d_out, int out_size, void* d_ws, size_t ws_size,
                              hipStream_t stream) {
    (void)in_sizes; (void)n_in; (void)out_size; (void)ws_size;

    const float* in_xr = (const float*)d_in[0];
    const float* in_xi = (const float*)d_in[1];
    PrepArgs pa;
    pa.Wr[0] = (const float*)d_in[2];  pa.Wi[0] = (const float*)d_in[3];   // q
    pa.Wr[1] = (const float*)d_in[4];  pa.Wi[1] = (const float*)d_in[5];   // k
    pa.Wr[2] = (const float*)d_in[6];  pa.Wi[2] = (const float*)d_in[7];   // v
    pa.Wr[3] = (const float*)d_in[8];  pa.Wi[3] = (const float*)d_in[9];   // o
    pa.Wr[4] = (const float*)d_in[10]; pa.Wi[4] = (const float*)d_in[11];  // f1
    pa.Wr[5] = (const float*)d_in[12]; pa.Wi[5] = (const float*)d_in[13];  // f2
    pa.br[0] = (const float*)d_in[14]; pa.bi[0] = (const float*)d_in[15];
    pa.br[1] = (const float*)d_in[16]; pa.bi[1] = (const float*)d_in[17];
    pa.br[2] = (const float*)d_in[18]; pa.bi[2] = (const float*)d_in[19];
    pa.br[3] = (const float*)d_in[20]; pa.bi[3] = (const float*)d_in[21];
    pa.br[4] = (const float*)d_in[22]; pa.bi[4] = (const float*)d_in[23];
    pa.br[5] = (const float*)d_in[24]; pa.bi[5] = (const float*)d_in[25];
    const float* ln1_grr = (const float*)d_in[26];
    const float* ln1_gii = (const float*)d_in[27];
    const float* ln2_grr = (const float*)d_in[28];
    const float* ln2_gii = (const float*)d_in[29];
    const float* ln1_gri = (const float*)d_in[30];
    const float* ln1_br  = (const float*)d_in[31];
    const float* ln1_bi  = (const float*)d_in[32];
    const float* ln2_gri = (const float*)d_in[33];
    const float* ln2_br  = (const float*)d_in[34];
    const float* ln2_bi  = (const float*)d_in[35];

    float* outr = (float*)d_out;
    float* outi = outr + BSD;

    char* ws = (char*)d_ws;
    unsigned short* Xh  = (unsigned short*)(ws);                    // 16 MiB each
    unsigned short* Qh  = (unsigned short*)(ws + 16777216);         // Q̂ / Ĥ (FFN hidden)
    unsigned short* Kh  = (unsigned short*)(ws + 2 * 16777216);     // K̂ / U (pre-LN bf16)
    unsigned short* Vth = (unsigned short*)(ws + 3 * 16777216);     // V̂t (κ-permuted keys)
    unsigned short* Ah  = (unsigned short*)(ws + 4 * 16777216);     // Â
    unsigned short* Ball = (unsigned short*)(ws + 5 * 16777216);    // 6 x 2 MiB
    float* biasall = (float*)(ws + 5 * 16777216 + 12582912);        // 24 KB
    unsigned short* Uh = Kh;
    unsigned short* Hh = Qh;

    init_cvt<<<ROWS * DIM / 1024, 256, 0, stream>>>(in_xr, in_xi, outr, outi, Xh);

    const dim3 pgrid(KHAT, 6);
    const dim3 qgrid(24, ROWS / 128);           // fused QKV: 1536 blocks
    const dim3 ggrid(KHAT / 128, ROWS / 128);   // (8, 64)
    const dim3 agrid(SEQ / 128, NH, NB);        // q-doubled: 512 blocks
    const int  lgrid = ROWS / 4;

    for (int l = 0; l < NL; ++l) {
        const size_t bo = (size_t)l * DIM;
        prep_kernel<<<pgrid, 256, 0, stream>>>(pa, Ball, biasall, l);

        unsigned short* Bo = Ball + (size_t)3 * KHAT * KHAT;
        unsigned short* B1 = Ball + (size_t)4 * KHAT * KHAT;
        unsigned short* B2 = Ball + (size_t)5 * KHAT * KHAT;

        gemm_qkv<<<qgrid, 256, 0, stream>>>(Xh, Ball, biasall, Qh, Kh, Vth);
        attn_mfma<<<agrid, 256, 0, stream>>>(Qh, Kh, Vth, Ah);
        gemm_mfma<false><<<ggrid, 256, 0, stream>>>(Ah, Bo, biasall + 3 * KHAT, Uh);
        cln_kernel<<<lgrid, 256, 0, stream>>>(Uh, outr, outi, Xh,
                                              ln1_grr + bo, ln1_gri + bo, ln1_gii + bo,
                                              ln1_br + bo, ln1_bi + bo);
        gemm_mfma<true><<<ggrid, 256, 0, stream>>>(Xh, B1, biasall + 4 * KHAT, Hh);
        gemm_mfma<false><<<ggrid, 256, 0, stream>>>(Hh, B2, biasall + 5 * KHAT, Uh);
        cln_kernel<<<lgrid, 256, 0, stream>>>(Uh, outr, outi, Xh,
                                              ln2_grr + bo, ln2_gri + bo, ln2_gii + bo,
                                              ln2_br + bo, ln2_bi + bo);
    }
}

// Round 10
// 1492.714 us; speedup vs baseline: 1.0037x; 1.0037x over previous
//
#include <hip/hip_runtime.h>
#include <cstddef>
#include <cstdint>

// ---------------------------------------------------------------- constants
constexpr int NB   = 8;
constexpr int SEQ  = 1024;
constexpr int DIM  = 512;
constexpr int NL   = 6;
constexpr int NH   = 8;
constexpr int HDIM = 64;
constexpr int ROWS = NB * SEQ;               // 8192
constexpr size_t BSD = (size_t)ROWS * DIM;   // 4,194,304
constexpr int KHAT = 1024;                   // concat K dim

typedef __attribute__((ext_vector_type(8))) short bfrag;   // 8 bf16 = 16B
typedef __attribute__((ext_vector_type(4))) float f32x4;
typedef __attribute__((ext_vector_type(4))) unsigned short us4;

__device__ __forceinline__ void f4a(const float4 v, float* a) {
    a[0] = v.x; a[1] = v.y; a[2] = v.z; a[3] = v.w;
}
__device__ __forceinline__ float4 a4f(const float* a) {
    float4 v; v.x = a[0]; v.y = a[1]; v.z = a[2]; v.w = a[3]; return v;
}
__device__ __forceinline__ unsigned short f2bf(float f) {
    union { float f; uint32_t u; } x{f};
    return (unsigned short)((x.u + 0x7fffu + ((x.u >> 16) & 1u)) >> 16);
}
__device__ __forceinline__ float bf2f(unsigned short u) {
    union { uint32_t u; float f; } x;
    x.u = (uint32_t)u << 16;
    return x.f;
}
__device__ __forceinline__ uint32_t cvtpk(float lo, float hi) {
    uint32_t r;
    asm("v_cvt_pk_bf16_f32 %0, %1, %2" : "=v"(r) : "v"(lo), "v"(hi));
    return r;
}
// async global->LDS DMA, 16B per lane; LDS dest = wave-uniform base + lane*16
__device__ __forceinline__ void gload16(const unsigned short* g, void* l) {
    __builtin_amdgcn_global_load_lds(
        (const __attribute__((address_space(1))) void*)g,
        (__attribute__((address_space(3))) void*)l, 16, 0, 0);
}

constexpr float ATT_SC = 0.125f * 1.44269504f;   // hd^-0.5 * log2(e), folded into Q

// ---------------------------------------------------------------- weight prep
struct PrepArgs {
    const float* Wr[6]; const float* Wi[6];
    const float* br[6]; const float* bi[6];
};

__global__ __launch_bounds__(256)
void prep_kernel(PrepArgs a, unsigned short* __restrict__ Ball,
                 float* __restrict__ biasall, int layer)
{
    const int lin = blockIdx.y;
    const int nh_ = blockIdx.x;           // ň
    const float* Wr = a.Wr[lin] + (size_t)layer * DIM * DIM;
    const float* Wi = a.Wi[lin] + (size_t)layer * DIM * DIM;

    bool real; int n0;
    if (lin < 3) { const int dh = nh_ & 127; real = dh < 64; n0 = (nh_ >> 7) * 64 + (dh & 63); }
    else         { real = nh_ < 512; n0 = nh_ & 511; }

    const int t = threadIdx.x;
    const int kk = (t * 4) & 511;
    const bool fh = t < 128;
    const float* src;
    float sgn = 1.f;
    if (fh) src = real ? Wr : Wi;
    else { if (real) { src = Wi; sgn = -1.f; } else src = Wr; }

    float v[4];
    f4a(*(const float4*)(src + (size_t)n0 * 512 + kk), v);
    us4 o;
    #pragma unroll
    for (int j = 0; j < 4; ++j) o[j] = f2bf(sgn * v[j]);
    *(us4*)(Ball + (size_t)lin * KHAT * KHAT + (size_t)nh_ * KHAT + t * 4) = o;
    if (t == 0)
        biasall[lin * KHAT + nh_] = real ? a.br[lin][layer * DIM + n0]
                                         : a.bi[lin][layer * DIM + n0];
}

// ---------------------------------------------------------------- fused QKV GEMM
//  One launch, N=3072 (Q|K|V). 128x128 tiles; 2 K-steps of 32 per barrier
//  pair via doubled LDS buffers. Q pre-scaled by ATT_SC; V̂t key-κ-permuted.
__global__ __launch_bounds__(256)
void gemm_qkv(const unsigned short* __restrict__ Xh,
              const unsigned short* __restrict__ Ball,
              const float* __restrict__ biasall,
              unsigned short* __restrict__ Qh,
              unsigned short* __restrict__ Kh,
              unsigned short* __restrict__ Vth)
{
    __shared__ __align__(16) unsigned short Asm[2][128 * 32];
    __shared__ __align__(16) unsigned short Bsm[2][128 * 32];

    const int t = threadIdx.x, lane = t & 63, w = t >> 6;
    const int wm = w >> 1, wn = w & 1;
    const int c = lane & 15, g = lane >> 4;

    int bid = blockIdx.y * 24 + blockIdx.x;
    bid = (bid & 7) * 192 + (bid >> 3);
    const int nblk = bid % 24, mblk = bid / 24;
    const int n0g = nblk * 128;          // 0..3071
    const int m0 = mblk * 128;
    const int lin = n0g >> 10;           // 0=Q 1=K 2=V
    const int n0 = n0g & 1023;
    const unsigned short* Bh = Ball + (size_t)lin * KHAT * KHAT;
    const float* bias = biasall + lin * KHAT;

    f32x4 acc[4][4];
    #pragma unroll
    for (int i = 0; i < 4; ++i)
        #pragma unroll
        for (int j = 0; j < 4; ++j) acc[i][j] = (f32x4){0.f, 0.f, 0.f, 0.f};

    const int srow = (w << 4) + (lane >> 2);
    const int scol = (lane & 3) * 8;
    const unsigned short* gA0 = Xh + (size_t)(m0 + srow) * KHAT + scol;
    const unsigned short* gA1 = Xh + (size_t)(m0 + 64 + srow) * KHAT + scol;
    const unsigned short* gB0 = Bh + (size_t)(n0 + srow) * KHAT + scol;
    const unsigned short* gB1 = Bh + (size_t)(n0 + 64 + srow) * KHAT + scol;
    char* aB0 = (char*)Asm[0] + (w << 10);
    char* aB1 = (char*)Asm[1] + (w << 10);
    char* bB0 = (char*)Bsm[0] + (w << 10);
    char* bB1 = (char*)Bsm[1] + (w << 10);

    for (int ks = 0; ks < 16; ++ks) {
        const int k0 = ks * 64;
        __syncthreads();
        gload16(gA0 + k0, aB0);
        gload16(gA1 + k0, aB0 + 4096);
        gload16(gB0 + k0, bB0);
        gload16(gB1 + k0, bB0 + 4096);
        gload16(gA0 + k0 + 32, aB1);
        gload16(gA1 + k0 + 32, aB1 + 4096);
        gload16(gB0 + k0 + 32, bB1);
        gload16(gB1 + k0 + 32, bB1 + 4096);
        __syncthreads();

        #pragma unroll
        for (int h = 0; h < 2; ++h) {
            bfrag af[4], bf2[4];
            #pragma unroll
            for (int mi = 0; mi < 4; ++mi)
                af[mi] = *(const bfrag*)(Asm[h] + (wm * 64 + mi * 16 + c) * 32 + g * 8);
            #pragma unroll
            for (int ni = 0; ni < 4; ++ni)
                bf2[ni] = *(const bfrag*)(Bsm[h] + (wn * 64 + ni * 16 + c) * 32 + g * 8);
            #pragma unroll
            for (int mi = 0; mi < 4; ++mi)
                #pragma unroll
                for (int ni = 0; ni < 4; ++ni)
                    acc[mi][ni] = __builtin_amdgcn_mfma_f32_16x16x32_bf16(
                        af[mi], bf2[ni], acc[mi][ni], 0, 0, 0);
        }
    }

    const int mbase = m0 + wm * 64;
    const int nbase = n0 + wn * 64;
    unsigned short* dqk = (lin == 0) ? Qh : Kh;
    #pragma unroll
    for (int mi = 0; mi < 4; ++mi) {
        #pragma unroll
        for (int ni = 0; ni < 4; ++ni) {
            const int n = nbase + ni * 16 + c;
            const float bv = bias[n];
            float v[4];
            #pragma unroll
            for (int r = 0; r < 4; ++r) {
                v[r] = acc[mi][ni][r] + bv;
                if (lin == 0) v[r] *= ATT_SC;   // fold softmax scale into Q
            }
            const int mrow = mbase + mi * 16 + g * 4;
            const int b = mrow >> 10, s = mrow & 1023;
            const int h = n >> 7, dh = n & 127;
            if (lin < 2) {
                const size_t a = ((size_t)(b * NH + h) * SEQ + s) * 128 + dh;
                #pragma unroll
                for (int r = 0; r < 4; ++r) dqk[a + (size_t)r * 128] = f2bf(v[r]);
            } else {
                // κ-permute: 4-key chunk ck within its 32-block -> slot (ck&3)<<1 | ck>>2
                const int ck = (s & 31) >> 2;
                const int sp = (s & ~31) | ((((ck & 3) << 1) | (ck >> 2)) << 2);
                const size_t a = ((size_t)(b * NH + h) * 128 + dh) * SEQ + sp;
                us4 o;
                #pragma unroll
                for (int r = 0; r < 4; ++r) o[r] = f2bf(v[r]);
                *(us4*)(Vth + a) = o;
            }
        }
    }
}

// ---------------------------------------------------------------- MFMA GEMM (bf16 out)
//  2 K-steps per barrier pair, doubled LDS buffers.
template <bool RELU>
__global__ __launch_bounds__(256)
void gemm_mfma(const unsigned short* __restrict__ Xh,
               const unsigned short* __restrict__ Bh,
               const float* __restrict__ bias,
               unsigned short* __restrict__ Yh)
{
    __shared__ __align__(16) unsigned short Asm[2][128 * 32];
    __shared__ __align__(16) unsigned short Bsm[2][128 * 32];

    const int t = threadIdx.x, lane = t & 63, w = t >> 6;
    const int wm = w >> 1, wn = w & 1;
    const int c = lane & 15, g = lane >> 4;

    int bid = blockIdx.y * 8 + blockIdx.x;
    bid = (bid & 7) * 64 + (bid >> 3);
    const int n0 = (bid & 7) * 128;
    const int m0 = (bid >> 3) * 128;

    f32x4 acc[4][4];
    #pragma unroll
    for (int i = 0; i < 4; ++i)
        #pragma unroll
        for (int j = 0; j < 4; ++j) acc[i][j] = (f32x4){0.f, 0.f, 0.f, 0.f};

    const int srow = (w << 4) + (lane >> 2);
    const int scol = (lane & 3) * 8;
    const unsigned short* gA0 = Xh + (size_t)(m0 + srow) * KHAT + scol;
    const unsigned short* gA1 = Xh + (size_t)(m0 + 64 + srow) * KHAT + scol;
    const unsigned short* gB0 = Bh + (size_t)(n0 + srow) * KHAT + scol;
    const unsigned short* gB1 = Bh + (size_t)(n0 + 64 + srow) * KHAT + scol;
    char* aB0 = (char*)Asm[0] + (w << 10);
    char* aB1 = (char*)Asm[1] + (w << 10);
    char* bB0 = (char*)Bsm[0] + (w << 10);
    char* bB1 = (char*)Bsm[1] + (w << 10);

    for (int ks = 0; ks < 16; ++ks) {
        const int k0 = ks * 64;
        __syncthreads();
        gload16(gA0 + k0, aB0);
        gload16(gA1 + k0, aB0 + 4096);
        gload16(gB0 + k0, bB0);
        gload16(gB1 + k0, bB0 + 4096);
        gload16(gA0 + k0 + 32, aB1);
        gload16(gA1 + k0 + 32, aB1 + 4096);
        gload16(gB0 + k0 + 32, bB1);
        gload16(gB1 + k0 + 32, bB1 + 4096);
        __syncthreads();

        #pragma unroll
        for (int h = 0; h < 2; ++h) {
            bfrag af[4], bf2[4];
            #pragma unroll
            for (int mi = 0; mi < 4; ++mi)
                af[mi] = *(const bfrag*)(Asm[h] + (wm * 64 + mi * 16 + c) * 32 + g * 8);
            #pragma unroll
            for (int ni = 0; ni < 4; ++ni)
                bf2[ni] = *(const bfrag*)(Bsm[h] + (wn * 64 + ni * 16 + c) * 32 + g * 8);
            #pragma unroll
            for (int mi = 0; mi < 4; ++mi)
                #pragma unroll
                for (int ni = 0; ni < 4; ++ni)
                    acc[mi][ni] = __builtin_amdgcn_mfma_f32_16x16x32_bf16(
                        af[mi], bf2[ni], acc[mi][ni], 0, 0, 0);
        }
    }

    const int mbase = m0 + wm * 64;
    const int nbase = n0 + wn * 64;
    #pragma unroll
    for (int mi = 0; mi < 4; ++mi) {
        #pragma unroll
        for (int ni = 0; ni < 4; ++ni) {
            const int n = nbase + ni * 16 + c;
            const float bv = bias[n];
            const int mrow = mbase + mi * 16 + g * 4;
            #pragma unroll
            for (int r = 0; r < 4; ++r) {
                float v = acc[mi][ni][r] + bv;
                if (RELU) v = fmaxf(v, 0.f);
                Yh[(size_t)(mrow + r) * KHAT + n] = f2bf(v);
            }
        }
    }
}

// ---------------------------------------------------------------- MFMA flash attention
//  q-doubled (4 waves x 32 q, 512 blocks) + LDS DOUBLE-BUFFER with ONE barrier
//  per tile: compute(buf p) || write next tile regs -> buf p^1, then barrier.
//  Staging writes are off the critical path; global loads hide under compute.
__global__ __launch_bounds__(256)
void attn_mfma(const unsigned short* __restrict__ Qh,
               const unsigned short* __restrict__ Kh,
               const unsigned short* __restrict__ Vth,
               unsigned short* __restrict__ Ah)
{
    __shared__ __align__(16) char smem[65536];   // 2 x (K 16KB + V 16KB)
    const int t    = threadIdx.x;
    const int lane = t & 63;
    const int wv   = t >> 6;
    const int c    = lane & 15;
    const int g    = lane >> 4;

    // 512 blocks; XCD chunk = 64 = 8 (b,h) pairs -> K/V fills one L2
    int bid = blockIdx.x + 8 * blockIdx.y + 64 * blockIdx.z;
    bid = (bid & 7) * 64 + (bid >> 3);
    const int q0 = (bid & 7) * 128;
    const int bh = bid >> 3;
    const int hh = bh & 7, bb = bh >> 3;
    const size_t qkb = (size_t)bh * SEQ * 128;
    const size_t vtb = (size_t)bh * 128 * SEQ;

    constexpr float THR = 11.0f;   // defer threshold (log2 units)

    bfrag qf[2][4];   // two q-groups of 16 rows each (B-operand), pre-scaled
    #pragma unroll
    for (int u = 0; u < 2; ++u) {
        const unsigned short* qp = Qh + qkb + (size_t)(q0 + wv * 32 + u * 16 + c) * 128 + g * 8;
        #pragma unroll
        for (int ks = 0; ks < 4; ++ks) qf[u][ks] = *(const bfrag*)(qp + ks * 32);
    }

    f32x4 oacc[2][8];
    #pragma unroll
    for (int u = 0; u < 2; ++u)
        #pragma unroll
        for (int i = 0; i < 8; ++i) oacc[u][i] = (f32x4){0.f, 0.f, 0.f, 0.f};
    float mrun[2] = {-1e30f, -1e30f}, lrun[2] = {0.f, 0.f};

    const int kkey = t >> 2, kq = t & 3;
    const unsigned short* kgp = Kh + qkb + (size_t)kkey * 128 + kq * 32;
    const int vd = t >> 1, vh2 = t & 1;
    const unsigned short* vgp = Vth + vtb + (size_t)vd * SEQ + vh2 * 32;

    const int kboff[4] = {
        (kkey * 256 + (kq * 32 + 0 * 8) * 2) ^ ((kkey & 7) << 4),
        (kkey * 256 + (kq * 32 + 1 * 8) * 2) ^ ((kkey & 7) << 4),
        (kkey * 256 + (kq * 32 + 2 * 8) * 2) ^ ((kkey & 7) << 4),
        (kkey * 256 + (kq * 32 + 3 * 8) * 2) ^ ((kkey & 7) << 4)};
    const int vboff[4] = {
        (vd * 128 + (vh2 * 32 + 0 * 8) * 2) ^ ((vd & 7) << 4),
        (vd * 128 + (vh2 * 32 + 1 * 8) * 2) ^ ((vd & 7) << 4),
        (vd * 128 + (vh2 * 32 + 2 * 8) * 2) ^ ((vd & 7) << 4),
        (vd * 128 + (vh2 * 32 + 3 * 8) * 2) ^ ((vd & 7) << 4)};

    // ---- prologue: load tile 0 into regs, write into buffer 0
    bfrag krg[4], vrg[4];
    #pragma unroll
    for (int j = 0; j < 4; ++j) krg[j] = *(const bfrag*)(kgp + j * 8);
    #pragma unroll
    for (int j = 0; j < 4; ++j) vrg[j] = *(const bfrag*)(vgp + j * 8);
    {
        char* Kw = smem;
        char* Vw = smem + 16384;
        #pragma unroll
        for (int j = 0; j < 4; ++j) *(bfrag*)(Kw + kboff[j]) = krg[j];
        #pragma unroll
        for (int j = 0; j < 4; ++j) *(bfrag*)(Vw + vboff[j]) = vrg[j];
    }
    __syncthreads();

    for (int tix = 0; tix < SEQ / 64; ++tix) {
        const int p = tix & 1;
        char* Ksm = smem + p * 32768;
        char* Vsm = Ksm + 16384;
        const bool more = (tix + 1) < SEQ / 64;

        // 1. issue next tile's global loads (latency hides under full compute)
        if (more) {
            const int kn = (tix + 1) * 64;
            #pragma unroll
            for (int j = 0; j < 4; ++j) krg[j] = *(const bfrag*)(kgp + (size_t)kn * 128 + j * 8);
            #pragma unroll
            for (int j = 0; j < 4; ++j) vrg[j] = *(const bfrag*)(vgp + kn + j * 8);
        }

        // 2. S^T = K̂ · Q̂ᵀ : K frags shared across both q-groups
        f32x4 sa[2][4];
        #pragma unroll
        for (int u = 0; u < 2; ++u)
            #pragma unroll
            for (int nt = 0; nt < 4; ++nt) sa[u][nt] = (f32x4){0.f, 0.f, 0.f, 0.f};
        __builtin_amdgcn_s_setprio(1);
        #pragma unroll
        for (int nt = 0; nt < 4; ++nt) {
            const int key = nt * 16 + c;
            bfrag kf[4];
            #pragma unroll
            for (int ks = 0; ks < 4; ++ks) {
                const int boff = (key * 256 + (ks * 32 + g * 8) * 2) ^ ((key & 7) << 4);
                kf[ks] = *(const bfrag*)(Ksm + boff);
            }
            #pragma unroll
            for (int u = 0; u < 2; ++u)
                #pragma unroll
                for (int ks = 0; ks < 4; ++ks)
                    sa[u][nt] = __builtin_amdgcn_mfma_f32_16x16x32_bf16(kf[ks], qf[u][ks], sa[u][nt], 0, 0, 0);
        }
        __builtin_amdgcn_s_setprio(0);

        // 3. lane-local softmax per q-group; pack P
        uint32_t pk0[2][4], pk1[2][4];
        #pragma unroll
        for (int u = 0; u < 2; ++u) {
            float mloc = sa[u][0][0];
            #pragma unroll
            for (int nt = 0; nt < 4; ++nt)
                #pragma unroll
                for (int r = 0; r < 4; ++r) mloc = fmaxf(mloc, sa[u][nt][r]);
            if (__any(mloc > mrun[u] + THR)) {
                float mt = mloc;
                mt = fmaxf(mt, __shfl_xor(mt, 16, 64));
                mt = fmaxf(mt, __shfl_xor(mt, 32, 64));
                const float mn = fmaxf(mrun[u], mt);
                const float fs = exp2f(mrun[u] - mn);
                mrun[u] = mn;
                lrun[u] *= fs;
                #pragma unroll
                for (int i = 0; i < 8; ++i) {
                    oacc[u][i][0] *= fs; oacc[u][i][1] *= fs;
                    oacc[u][i][2] *= fs; oacc[u][i][3] *= fs;
                }
            }
            float ps = 0.f;
            #pragma unroll
            for (int nt = 0; nt < 4; ++nt) {
                float p0 = exp2f(sa[u][nt][0] - mrun[u]);
                float p1 = exp2f(sa[u][nt][1] - mrun[u]);
                float p2 = exp2f(sa[u][nt][2] - mrun[u]);
                float p3 = exp2f(sa[u][nt][3] - mrun[u]);
                ps += (p0 + p1) + (p2 + p3);
                pk0[u][nt] = cvtpk(p0, p1);
                pk1[u][nt] = cvtpk(p2, p3);
            }
            ps += __shfl_xor(ps, 16, 64);
            ps += __shfl_xor(ps, 32, 64);
            lrun[u] += ps;
        }

        // 4. Oᵀ += V̂ᵀ · Pᵀ : V frags shared across both q-groups
        __builtin_amdgcn_s_setprio(1);
        #pragma unroll
        for (int k2 = 0; k2 < 2; ++k2) {
            union { uint32_t u[4]; bfrag f; } pb0, pb1;
            pb0.u[0] = pk0[0][2 * k2]; pb0.u[1] = pk1[0][2 * k2];
            pb0.u[2] = pk0[0][2 * k2 + 1]; pb0.u[3] = pk1[0][2 * k2 + 1];
            pb1.u[0] = pk0[1][2 * k2]; pb1.u[1] = pk1[1][2 * k2];
            pb1.u[2] = pk0[1][2 * k2 + 1]; pb1.u[3] = pk1[1][2 * k2 + 1];
            const int kb2 = (k2 * 32 + g * 8) * 2;
            #pragma unroll
            for (int mtl = 0; mtl < 8; ++mtl) {
                const int d = mtl * 16 + c;
                const bfrag va = *(const bfrag*)(Vsm + ((d * 128 + kb2) ^ ((d & 7) << 4)));
                oacc[0][mtl] = __builtin_amdgcn_mfma_f32_16x16x32_bf16(va, pb0.f, oacc[0][mtl], 0, 0, 0);
                oacc[1][mtl] = __builtin_amdgcn_mfma_f32_16x16x32_bf16(va, pb1.f, oacc[1][mtl], 0, 0, 0);
            }
        }
        __builtin_amdgcn_s_setprio(0);

        // 5. write next tile into the OTHER buffer (no barrier needed before:
        //    all waves finished reading it before the PREVIOUS barrier)
        if (more) {
            char* Kw = smem + (p ^ 1) * 32768;
            char* Vw = Kw + 16384;
            #pragma unroll
            for (int j = 0; j < 4; ++j) *(bfrag*)(Kw + kboff[j]) = krg[j];
            #pragma unroll
            for (int j = 0; j < 4; ++j) *(bfrag*)(Vw + vboff[j]) = vrg[j];
        }
        __syncthreads();   // single barrier per tile
    }

    // normalize
    #pragma unroll
    for (int u = 0; u < 2; ++u) {
        const float ic = 1.0f / lrun[u];
        #pragma unroll
        for (int i = 0; i < 8; ++i) {
            oacc[u][i][0] *= ic; oacc[u][i][1] *= ic;
            oacc[u][i][2] *= ic; oacc[u][i][3] *= ic;
        }
    }
    __syncthreads();   // K/V LDS no longer needed; reuse as transpose scratch
    float* Ox = (float*)(smem + wv * 8192);   // per-wave [128 d][16 q]
    const int q = lane >> 2, qt = lane & 3;
    const int colbase = (qt >> 1) * 512 + hh * 64 + (qt & 1) * 32;
    #pragma unroll
    for (int u = 0; u < 2; ++u) {
        #pragma unroll
        for (int mtl = 0; mtl < 8; ++mtl)
            #pragma unroll
            for (int r = 0; r < 4; ++r)
                Ox[(mtl * 16 + 4 * g + r) * 16 + c] = oacc[u][mtl][r];
        asm volatile("s_waitcnt lgkmcnt(0)" ::: "memory");
        __builtin_amdgcn_sched_barrier(0);

        const size_t rowm = (size_t)bb * SEQ + q0 + wv * 32 + u * 16 + q;
        unsigned short* dst = Ah + rowm * KHAT + colbase;
        #pragma unroll
        for (int j = 0; j < 8; ++j) {
            us4 o;
            #pragma unroll
            for (int e = 0; e < 4; ++e) o[e] = f2bf(Ox[(qt * 32 + j * 4 + e) * 16 + q]);
            *(us4*)(dst + j * 4) = o;
        }
        asm volatile("s_waitcnt lgkmcnt(0)" ::: "memory");   // drain before next-u overwrite
        __builtin_amdgcn_sched_barrier(0);
    }
}

// ---------------------------------------------------------------- complex LayerNorm
__global__ __launch_bounds__(256)
void cln_kernel(const unsigned short* __restrict__ U,
                float* __restrict__ Xr, float* __restrict__ Xi,
                unsigned short* __restrict__ Xh,
                const float* __restrict__ Grr, const float* __restrict__ Gri,
                const float* __restrict__ Gii, const float* __restrict__ Bbr,
                const float* __restrict__ Bbi)
{
    const int lane = threadIdx.x & 63;
    const int row  = blockIdx.x * 4 + (threadIdx.x >> 6);
    const size_t off = (size_t)row * DIM;
    const int c0 = lane * 4;
    const int c1 = 256 + lane * 4;

    float xr[8], xi[8];
    {
        const unsigned short* up = U + (size_t)row * KHAT;
        us4 a0 = *(const us4*)(up + c0);
        us4 a1 = *(const us4*)(up + c1);
        us4 b0 = *(const us4*)(up + 512 + c0);
        us4 b1 = *(const us4*)(up + 512 + c1);
        float t0[4], t1[4];
        f4a(*(const float4*)&Xr[off + c0], t0);
        f4a(*(const float4*)&Xr[off + c1], t1);
        #pragma unroll
        for (int j = 0; j < 4; ++j) { xr[j] = bf2f(a0[j]) + t0[j]; xr[4 + j] = bf2f(a1[j]) + t1[j]; }
        f4a(*(const float4*)&Xi[off + c0], t0);
        f4a(*(const float4*)&Xi[off + c1], t1);
        #pragma unroll
        for (int j = 0; j < 4; ++j) { xi[j] = bf2f(b0[j]) + t0[j]; xi[4 + j] = bf2f(b1[j]) + t1[j]; }
    }

    float sr = 0.f, si = 0.f, srr = 0.f, sii = 0.f, sri = 0.f;
    #pragma unroll
    for (int j = 0; j < 8; ++j) {
        sr += xr[j]; si += xi[j];
        srr = fmaf(xr[j], xr[j], srr);
        sii = fmaf(xi[j], xi[j], sii);
        sri = fmaf(xr[j], xi[j], sri);
    }
    #pragma unroll
    for (int m = 32; m >= 1; m >>= 1) {
        sr  += __shfl_xor(sr,  m, 64);
        si  += __shfl_xor(si,  m, 64);
        srr += __shfl_xor(srr, m, 64);
        sii += __shfl_xor(sii, m, 64);
        sri += __shfl_xor(sri, m, 64);
    }

    const float inv_d = 1.0f / DIM;
    const float mr = sr * inv_d, mi = si * inv_d;
    const float Vrr = srr * inv_d - mr * mr + 1e-5f;
    const float Vii = sii * inv_d - mi * mi + 1e-5f;
    const float Vri = sri * inv_d - mr * mi;
    const float s  = sqrtf(Vrr * Vii - Vri * Vri);
    const float tt = sqrtf(Vrr + Vii + 2.0f * s);
    const float ist = 1.0f / (s * tt);
    const float Wrr = (Vii + s) * ist;
    const float Wii = (Vrr + s) * ist;
    const float Wri = -Vri * ist;

    #pragma unroll
    for (int half = 0; half < 2; ++half) {
        const int c = half ? c1 : c0;
        float grr[4], gri[4], gii[4], pbr[4], pbi[4];
        f4a(*(const float4*)&Grr[c], grr);
        f4a(*(const float4*)&Gri[c], gri);
        f4a(*(const float4*)&Gii[c], gii);
        f4a(*(const float4*)&Bbr[c], pbr);
        f4a(*(const float4*)&Bbi[c], pbi);
        float outr[4], outi[4];
        #pragma unroll
        for (int j = 0; j < 4; ++j) {
            const int idx = half * 4 + j;
            const float cr = xr[idx] - mr;
            const float ci = xi[idx] - mi;
            const float hr = Wrr * cr + Wri * ci;
            const float hi = Wri * cr + Wii * ci;
            outr[j] = fmaf(grr[j], hr, fmaf(gri[j], hi, pbr[j]));
            outi[j] = fmaf(gri[j], hr, fmaf(gii[j], hi, pbi[j]));
        }
        *(float4*)&Xr[off + c] = a4f(outr);
        *(float4*)&Xi[off + c] = a4f(outi);
        us4 hr_, hi_;
        #pragma unroll
        for (int j = 0; j < 4; ++j) { hr_[j] = f2bf(outr[j]); hi_[j] = f2bf(outi[j]); }
        *(us4*)(Xh + (size_t)row * KHAT + c)       = hr_;
        *(us4*)(Xh + (size_t)row * KHAT + 512 + c) = hi_;
    }
}

// ---------------------------------------------------------------- init: copy + bf16 X̂
__global__ __launch_bounds__(256)
void init_cvt(const float* __restrict__ xr, const float* __restrict__ xi,
              float* __restrict__ outr, float* __restrict__ outi,
              unsigned short* __restrict__ Xh)
{
    const size_t i = ((size_t)blockIdx.x * 256 + threadIdx.x) * 4;
    float vr[4], vi[4];
    f4a(*(const float4*)(xr + i), vr);
    f4a(*(const float4*)(xi + i), vi);
    *(float4*)(outr + i) = a4f(vr);
    *(float4*)(outi + i) = a4f(vi);
    const size_t m = i >> 9;
    const int k = (int)(i & 511);
    us4 a, b;
    #pragma unroll
    for (int j = 0; j < 4; ++j) { a[j] = f2bf(vr[j]); b[j] = f2bf(vi[j]); }
    *(us4*)(Xh + m * KHAT + k)       = a;
    *(us4*)(Xh + m * KHAT + 512 + k) = b;
}

// ---------------------------------------------------------------- host
extern "C" void kernel_launch(void* const* d_in, const int* in_sizes, int n_in,
                              void* d_out, int out_size, void* d_ws, size_t ws_size,
                              hipStream_t stream) {
    (void)in_sizes; (void)n_in; (void)out_size; (void)ws_size;

    const float* in_xr = (const float*)d_in[0];
    const float* in_xi = (const float*)d_in[1];
    PrepArgs pa;
    pa.Wr[0] = (const float*)d_in[2];  pa.Wi[0] = (const float*)d_in[3];   // q
    pa.Wr[1] = (const float*)d_in[4];  pa.Wi[1] = (const float*)d_in[5];   // k
    pa.Wr[2] = (const float*)d_in[6];  pa.Wi[2] = (const float*)d_in[7];   // v
    pa.Wr[3] = (const float*)d_in[8];  pa.Wi[3] = (const float*)d_in[9];   // o
    pa.Wr[4] = (const float*)d_in[10]; pa.Wi[4] = (const float*)d_in[11];  // f1
    pa.Wr[5] = (const float*)d_in[12]; pa.Wi[5] = (const float*)d_in[13];  // f2
    pa.br[0] = (const float*)d_in[14]; pa.bi[0] = (const float*)d_in[15];
    pa.br[1] = (const float*)d_in[16]; pa.bi[1] = (const float*)d_in[17];
    pa.br[2] = (const float*)d_in[18]; pa.bi[2] = (const float*)d_in[19];
    pa.br[3] = (const float*)d_in[20]; pa.bi[3] = (const float*)d_in[21];
    pa.br[4] = (const float*)d_in[22]; pa.bi[4] = (const float*)d_in[23];
    pa.br[5] = (const float*)d_in[24]; pa.bi[5] = (const float*)d_in[25];
    const float* ln1_grr = (const float*)d_in[26];
    const float* ln1_gii = (const float*)d_in[27];
    const float* ln2_grr = (const float*)d_in[28];
    const float* ln2_gii = (const float*)d_in[29];
    const float* ln1_gri = (const float*)d_in[30];
    const float* ln1_br  = (const float*)d_in[31];
    const float* ln1_bi  = (const float*)d_in[32];
    const float* ln2_gri = (const float*)d_in[33];
    const float* ln2_br  = (const float*)d_in[34];
    const float* ln2_bi  = (const float*)d_in[35];

    float* outr = (float*)d_out;
    float* outi = outr + BSD;

    char* ws = (char*)d_ws;
    unsigned short* Xh  = (unsigned short*)(ws);                    // 16 MiB each
    unsigned short* Qh  = (unsigned short*)(ws + 16777216);         // Q̂ / Ĥ (FFN hidden)
    unsigned short* Kh  = (unsigned short*)(ws + 2 * 16777216);     // K̂ / U (pre-LN bf16)
    unsigned short* Vth = (unsigned short*)(ws + 3 * 16777216);     // V̂t (κ-permuted keys)
    unsigned short* Ah  = (unsigned short*)(ws + 4 * 16777216);     // Â
    unsigned short* Ball = (unsigned short*)(ws + 5 * 16777216);    // 6 x 2 MiB
    float* biasall = (float*)(ws + 5 * 16777216 + 12582912);        // 24 KB
    unsigned short* Uh = Kh;
    unsigned short* Hh = Qh;

    init_cvt<<<ROWS * DIM / 1024, 256, 0, stream>>>(in_xr, in_xi, outr, outi, Xh);

    const dim3 pgrid(KHAT, 6);
    const dim3 qgrid(24, ROWS / 128);           // fused QKV: 1536 blocks
    const dim3 ggrid(KHAT / 128, ROWS / 128);   // (8, 64)
    const dim3 agrid(SEQ / 128, NH, NB);        // q-doubled: 512 blocks
    const int  lgrid = ROWS / 4;

    for (int l = 0; l < NL; ++l) {
        const size_t bo = (size_t)l * DIM;
        prep_kernel<<<pgrid, 256, 0, stream>>>(pa, Ball, biasall, l);

        unsigned short* Bo = Ball + (size_t)3 * KHAT * KHAT;
        unsigned short* B1 = Ball + (size_t)4 * KHAT * KHAT;
        unsigned short* B2 = Ball + (size_t)5 * KHAT * KHAT;

        gemm_qkv<<<qgrid, 256, 0, stream>>>(Xh, Ball, biasall, Qh, Kh, Vth);
        attn_mfma<<<agrid, 256, 0, stream>>>(Qh, Kh, Vth, Ah);
        gemm_mfma<false><<<ggrid, 256, 0, stream>>>(Ah, Bo, biasall + 3 * KHAT, Uh);
        cln_kernel<<<lgrid, 256, 0, stream>>>(Uh, outr, outi, Xh,
                                              ln1_grr + bo, ln1_gri + bo, ln1_gii + bo,
                                              ln1_br + bo, ln1_bi + bo);
        gemm_mfma<true><<<ggrid, 256, 0, stream>>>(Xh, B1, biasall + 4 * KHAT, Hh);
        gemm_mfma<false><<<ggrid, 256, 0, stream>>>(Hh, B2, biasall + 5 * KHAT, Uh);
        cln_kernel<<<lgrid, 256, 0, stream>>>(Uh, outr, outi, Xh,
                                              ln2_grr + bo, ln2_gri + bo, ln2_gii + bo,
                                              ln2_br + bo, ln2_bi + bo);
    }
}

// Round 11
// 1413.550 us; speedup vs baseline: 1.0599x; 1.0560x over previous
//
#include <hip/hip_runtime.h>
#include <cstddef>
#include <cstdint>

// ---------------------------------------------------------------- constants
constexpr int NB   = 8;
constexpr int SEQ  = 1024;
constexpr int DIM  = 512;
constexpr int NL   = 6;
constexpr int NH   = 8;
constexpr int HDIM = 64;
constexpr int ROWS = NB * SEQ;               // 8192
constexpr size_t BSD = (size_t)ROWS * DIM;   // 4,194,304
constexpr int KHAT = 1024;                   // concat K dim

typedef __attribute__((ext_vector_type(8))) short bfrag;   // 8 bf16 = 16B
typedef __attribute__((ext_vector_type(4))) float f32x4;
typedef __attribute__((ext_vector_type(4))) unsigned short us4;

__device__ __forceinline__ void f4a(const float4 v, float* a) {
    a[0] = v.x; a[1] = v.y; a[2] = v.z; a[3] = v.w;
}
__device__ __forceinline__ float4 a4f(const float* a) {
    float4 v; v.x = a[0]; v.y = a[1]; v.z = a[2]; v.w = a[3]; return v;
}
__device__ __forceinline__ unsigned short f2bf(float f) {
    union { float f; uint32_t u; } x{f};
    return (unsigned short)((x.u + 0x7fffu + ((x.u >> 16) & 1u)) >> 16);
}
__device__ __forceinline__ float bf2f(unsigned short u) {
    union { uint32_t u; float f; } x;
    x.u = (uint32_t)u << 16;
    return x.f;
}
__device__ __forceinline__ uint32_t cvtpk(float lo, float hi) {
    uint32_t r;
    asm("v_cvt_pk_bf16_f32 %0, %1, %2" : "=v"(r) : "v"(lo), "v"(hi));
    return r;
}
// async global->LDS DMA, 16B per lane; LDS dest = wave-uniform base + lane*16
__device__ __forceinline__ void gload16(const unsigned short* g, void* l) {
    __builtin_amdgcn_global_load_lds(
        (const __attribute__((address_space(1))) void*)g,
        (__attribute__((address_space(3))) void*)l, 16, 0, 0);
}

constexpr float ATT_SC = 0.125f * 1.44269504f;   // hd^-0.5 * log2(e), folded into Q

// ---------------------------------------------------------------- weight prep
struct PrepArgs {
    const float* Wr[6]; const float* Wi[6];
    const float* br[6]; const float* bi[6];
};

__global__ __launch_bounds__(256)
void prep_kernel(PrepArgs a, unsigned short* __restrict__ Ball,
                 float* __restrict__ biasall, int layer)
{
    const int lin = blockIdx.y;
    const int nh_ = blockIdx.x;           // ň
    const float* Wr = a.Wr[lin] + (size_t)layer * DIM * DIM;
    const float* Wi = a.Wi[lin] + (size_t)layer * DIM * DIM;

    bool real; int n0;
    if (lin < 3) { const int dh = nh_ & 127; real = dh < 64; n0 = (nh_ >> 7) * 64 + (dh & 63); }
    else         { real = nh_ < 512; n0 = nh_ & 511; }

    const int t = threadIdx.x;
    const int kk = (t * 4) & 511;
    const bool fh = t < 128;
    const float* src;
    float sgn = 1.f;
    if (fh) src = real ? Wr : Wi;
    else { if (real) { src = Wi; sgn = -1.f; } else src = Wr; }

    float v[4];
    f4a(*(const float4*)(src + (size_t)n0 * 512 + kk), v);
    us4 o;
    #pragma unroll
    for (int j = 0; j < 4; ++j) o[j] = f2bf(sgn * v[j]);
    *(us4*)(Ball + (size_t)lin * KHAT * KHAT + (size_t)nh_ * KHAT + t * 4) = o;
    if (t == 0)
        biasall[lin * KHAT + nh_] = real ? a.br[lin][layer * DIM + n0]
                                         : a.bi[lin][layer * DIM + n0];
}

// ---------------------------------------------------------------- fused QKV GEMM
//  One launch, N=3072 (Q|K|V). 128x128 tiles; 2 K-steps of 32 per barrier
//  pair via doubled LDS buffers. Q pre-scaled by ATT_SC; V̂t key-κ-permuted.
__global__ __launch_bounds__(256)
void gemm_qkv(const unsigned short* __restrict__ Xh,
              const unsigned short* __restrict__ Ball,
              const float* __restrict__ biasall,
              unsigned short* __restrict__ Qh,
              unsigned short* __restrict__ Kh,
              unsigned short* __restrict__ Vth)
{
    __shared__ __align__(16) unsigned short Asm[2][128 * 32];
    __shared__ __align__(16) unsigned short Bsm[2][128 * 32];

    const int t = threadIdx.x, lane = t & 63, w = t >> 6;
    const int wm = w >> 1, wn = w & 1;
    const int c = lane & 15, g = lane >> 4;

    int bid = blockIdx.y * 24 + blockIdx.x;
    bid = (bid & 7) * 192 + (bid >> 3);
    const int nblk = bid % 24, mblk = bid / 24;
    const int n0g = nblk * 128;          // 0..3071
    const int m0 = mblk * 128;
    const int lin = n0g >> 10;           // 0=Q 1=K 2=V
    const int n0 = n0g & 1023;
    const unsigned short* Bh = Ball + (size_t)lin * KHAT * KHAT;
    const float* bias = biasall + lin * KHAT;

    f32x4 acc[4][4];
    #pragma unroll
    for (int i = 0; i < 4; ++i)
        #pragma unroll
        for (int j = 0; j < 4; ++j) acc[i][j] = (f32x4){0.f, 0.f, 0.f, 0.f};

    const int srow = (w << 4) + (lane >> 2);
    const int scol = (lane & 3) * 8;
    const unsigned short* gA0 = Xh + (size_t)(m0 + srow) * KHAT + scol;
    const unsigned short* gA1 = Xh + (size_t)(m0 + 64 + srow) * KHAT + scol;
    const unsigned short* gB0 = Bh + (size_t)(n0 + srow) * KHAT + scol;
    const unsigned short* gB1 = Bh + (size_t)(n0 + 64 + srow) * KHAT + scol;
    char* aB0 = (char*)Asm[0] + (w << 10);
    char* aB1 = (char*)Asm[1] + (w << 10);
    char* bB0 = (char*)Bsm[0] + (w << 10);
    char* bB1 = (char*)Bsm[1] + (w << 10);

    for (int ks = 0; ks < 16; ++ks) {
        const int k0 = ks * 64;
        __syncthreads();
        gload16(gA0 + k0, aB0);
        gload16(gA1 + k0, aB0 + 4096);
        gload16(gB0 + k0, bB0);
        gload16(gB1 + k0, bB0 + 4096);
        gload16(gA0 + k0 + 32, aB1);
        gload16(gA1 + k0 + 32, aB1 + 4096);
        gload16(gB0 + k0 + 32, bB1);
        gload16(gB1 + k0 + 32, bB1 + 4096);
        __syncthreads();

        #pragma unroll
        for (int h = 0; h < 2; ++h) {
            bfrag af[4], bf2[4];
            #pragma unroll
            for (int mi = 0; mi < 4; ++mi)
                af[mi] = *(const bfrag*)(Asm[h] + (wm * 64 + mi * 16 + c) * 32 + g * 8);
            #pragma unroll
            for (int ni = 0; ni < 4; ++ni)
                bf2[ni] = *(const bfrag*)(Bsm[h] + (wn * 64 + ni * 16 + c) * 32 + g * 8);
            #pragma unroll
            for (int mi = 0; mi < 4; ++mi)
                #pragma unroll
                for (int ni = 0; ni < 4; ++ni)
                    acc[mi][ni] = __builtin_amdgcn_mfma_f32_16x16x32_bf16(
                        af[mi], bf2[ni], acc[mi][ni], 0, 0, 0);
        }
    }

    const int mbase = m0 + wm * 64;
    const int nbase = n0 + wn * 64;
    unsigned short* dqk = (lin == 0) ? Qh : Kh;
    #pragma unroll
    for (int mi = 0; mi < 4; ++mi) {
        #pragma unroll
        for (int ni = 0; ni < 4; ++ni) {
            const int n = nbase + ni * 16 + c;
            const float bv = bias[n];
            float v[4];
            #pragma unroll
            for (int r = 0; r < 4; ++r) {
                v[r] = acc[mi][ni][r] + bv;
                if (lin == 0) v[r] *= ATT_SC;   // fold softmax scale into Q
            }
            const int mrow = mbase + mi * 16 + g * 4;
            const int b = mrow >> 10, s = mrow & 1023;
            const int h = n >> 7, dh = n & 127;
            if (lin < 2) {
                const size_t a = ((size_t)(b * NH + h) * SEQ + s) * 128 + dh;
                #pragma unroll
                for (int r = 0; r < 4; ++r) dqk[a + (size_t)r * 128] = f2bf(v[r]);
            } else {
                // κ-permute: 4-key chunk ck within its 32-block -> slot (ck&3)<<1 | ck>>2
                const int ck = (s & 31) >> 2;
                const int sp = (s & ~31) | ((((ck & 3) << 1) | (ck >> 2)) << 2);
                const size_t a = ((size_t)(b * NH + h) * 128 + dh) * SEQ + sp;
                us4 o;
                #pragma unroll
                for (int r = 0; r < 4; ++r) o[r] = f2bf(v[r]);
                *(us4*)(Vth + a) = o;
            }
        }
    }
}

// ---------------------------------------------------------------- MFMA GEMM (bf16 out)
//  2 K-steps per barrier pair, doubled LDS buffers.
template <bool RELU>
__global__ __launch_bounds__(256)
void gemm_mfma(const unsigned short* __restrict__ Xh,
               const unsigned short* __restrict__ Bh,
               const float* __restrict__ bias,
               unsigned short* __restrict__ Yh)
{
    __shared__ __align__(16) unsigned short Asm[2][128 * 32];
    __shared__ __align__(16) unsigned short Bsm[2][128 * 32];

    const int t = threadIdx.x, lane = t & 63, w = t >> 6;
    const int wm = w >> 1, wn = w & 1;
    const int c = lane & 15, g = lane >> 4;

    int bid = blockIdx.y * 8 + blockIdx.x;
    bid = (bid & 7) * 64 + (bid >> 3);
    const int n0 = (bid & 7) * 128;
    const int m0 = (bid >> 3) * 128;

    f32x4 acc[4][4];
    #pragma unroll
    for (int i = 0; i < 4; ++i)
        #pragma unroll
        for (int j = 0; j < 4; ++j) acc[i][j] = (f32x4){0.f, 0.f, 0.f, 0.f};

    const int srow = (w << 4) + (lane >> 2);
    const int scol = (lane & 3) * 8;
    const unsigned short* gA0 = Xh + (size_t)(m0 + srow) * KHAT + scol;
    const unsigned short* gA1 = Xh + (size_t)(m0 + 64 + srow) * KHAT + scol;
    const unsigned short* gB0 = Bh + (size_t)(n0 + srow) * KHAT + scol;
    const unsigned short* gB1 = Bh + (size_t)(n0 + 64 + srow) * KHAT + scol;
    char* aB0 = (char*)Asm[0] + (w << 10);
    char* aB1 = (char*)Asm[1] + (w << 10);
    char* bB0 = (char*)Bsm[0] + (w << 10);
    char* bB1 = (char*)Bsm[1] + (w << 10);

    for (int ks = 0; ks < 16; ++ks) {
        const int k0 = ks * 64;
        __syncthreads();
        gload16(gA0 + k0, aB0);
        gload16(gA1 + k0, aB0 + 4096);
        gload16(gB0 + k0, bB0);
        gload16(gB1 + k0, bB0 + 4096);
        gload16(gA0 + k0 + 32, aB1);
        gload16(gA1 + k0 + 32, aB1 + 4096);
        gload16(gB0 + k0 + 32, bB1);
        gload16(gB1 + k0 + 32, bB1 + 4096);
        __syncthreads();

        #pragma unroll
        for (int h = 0; h < 2; ++h) {
            bfrag af[4], bf2[4];
            #pragma unroll
            for (int mi = 0; mi < 4; ++mi)
                af[mi] = *(const bfrag*)(Asm[h] + (wm * 64 + mi * 16 + c) * 32 + g * 8);
            #pragma unroll
            for (int ni = 0; ni < 4; ++ni)
                bf2[ni] = *(const bfrag*)(Bsm[h] + (wn * 64 + ni * 16 + c) * 32 + g * 8);
            #pragma unroll
            for (int mi = 0; mi < 4; ++mi)
                #pragma unroll
                for (int ni = 0; ni < 4; ++ni)
                    acc[mi][ni] = __builtin_amdgcn_mfma_f32_16x16x32_bf16(
                        af[mi], bf2[ni], acc[mi][ni], 0, 0, 0);
        }
    }

    const int mbase = m0 + wm * 64;
    const int nbase = n0 + wn * 64;
    #pragma unroll
    for (int mi = 0; mi < 4; ++mi) {
        #pragma unroll
        for (int ni = 0; ni < 4; ++ni) {
            const int n = nbase + ni * 16 + c;
            const float bv = bias[n];
            const int mrow = mbase + mi * 16 + g * 4;
            #pragma unroll
            for (int r = 0; r < 4; ++r) {
                float v = acc[mi][ni][r] + bv;
                if (RELU) v = fmaxf(v, 0.f);
                Yh[(size_t)(mrow + r) * KHAT + n] = f2bf(v);
            }
        }
    }
}

// ---------------------------------------------------------------- MFMA flash attention
//  (round-9 frozen structure) q-doubled: 4 waves x 32 q (QBLK=128), 512 blocks.
//  K/V frags reused across both q-groups. K+V in LDS (XOR-swizzled), swapped
//  QK^T, lane-local softmax, P in registers, κ-permuted V, defer-max, T14, T5.
__global__ __launch_bounds__(256)
void attn_mfma(const unsigned short* __restrict__ Qh,
               const unsigned short* __restrict__ Kh,
               const unsigned short* __restrict__ Vth,
               unsigned short* __restrict__ Ah)
{
    __shared__ __align__(16) char smem[32768];
    char* Ksm = smem;            // [64 key][128 d] bf16, XOR-swizzled, 16KB
    char* Vsm = smem + 16384;    // [128 d][64 slot] bf16, XOR-swizzled, 16KB
    const int t    = threadIdx.x;
    const int lane = t & 63;
    const int wv   = t >> 6;
    const int c    = lane & 15;
    const int g    = lane >> 4;

    // 512 blocks; XCD chunk = 64 = 8 (b,h) pairs -> K/V fills one L2
    int bid = blockIdx.x + 8 * blockIdx.y + 64 * blockIdx.z;
    bid = (bid & 7) * 64 + (bid >> 3);
    const int q0 = (bid & 7) * 128;
    const int bh = bid >> 3;
    const int hh = bh & 7, bb = bh >> 3;
    const size_t qkb = (size_t)bh * SEQ * 128;
    const size_t vtb = (size_t)bh * 128 * SEQ;

    constexpr float THR = 11.0f;   // defer threshold (log2 units)

    bfrag qf[2][4];   // two q-groups of 16 rows each (B-operand), pre-scaled
    #pragma unroll
    for (int u = 0; u < 2; ++u) {
        const unsigned short* qp = Qh + qkb + (size_t)(q0 + wv * 32 + u * 16 + c) * 128 + g * 8;
        #pragma unroll
        for (int ks = 0; ks < 4; ++ks) qf[u][ks] = *(const bfrag*)(qp + ks * 32);
    }

    f32x4 oacc[2][8];
    #pragma unroll
    for (int u = 0; u < 2; ++u)
        #pragma unroll
        for (int i = 0; i < 8; ++i) oacc[u][i] = (f32x4){0.f, 0.f, 0.f, 0.f};
    float mrun[2] = {-1e30f, -1e30f}, lrun[2] = {0.f, 0.f};

    const int kkey = t >> 2, kq = t & 3;
    const unsigned short* kgp = Kh + qkb + (size_t)kkey * 128 + kq * 32;
    const int vd = t >> 1, vh2 = t & 1;
    const unsigned short* vgp = Vth + vtb + (size_t)vd * SEQ + vh2 * 32;

    bfrag krg[4], vrg[4];
    #pragma unroll
    for (int j = 0; j < 4; ++j) krg[j] = *(const bfrag*)(kgp + j * 8);
    #pragma unroll
    for (int j = 0; j < 4; ++j) vrg[j] = *(const bfrag*)(vgp + j * 8);

    for (int k0 = 0; k0 < SEQ; k0 += 64) {
        __syncthreads();   // prior-iter LDS reads done
        #pragma unroll
        for (int j = 0; j < 4; ++j) {
            const int boff = (kkey * 256 + (kq * 32 + j * 8) * 2) ^ ((kkey & 7) << 4);
            *(bfrag*)(Ksm + boff) = krg[j];
        }
        #pragma unroll
        for (int j = 0; j < 4; ++j) {
            const int boff = (vd * 128 + (vh2 * 32 + j * 8) * 2) ^ ((vd & 7) << 4);
            *(bfrag*)(Vsm + boff) = vrg[j];
        }
        __syncthreads();

        if (k0 + 64 < SEQ) {   // T14: next-tile loads hide under compute
            const int kn = k0 + 64;
            #pragma unroll
            for (int j = 0; j < 4; ++j) krg[j] = *(const bfrag*)(kgp + (size_t)kn * 128 + j * 8);
            #pragma unroll
            for (int j = 0; j < 4; ++j) vrg[j] = *(const bfrag*)(vgp + kn + j * 8);
        }

        // ---- S^T = K̂ · Q̂ᵀ : K frags shared across both q-groups
        f32x4 sa[2][4];
        #pragma unroll
        for (int u = 0; u < 2; ++u)
            #pragma unroll
            for (int nt = 0; nt < 4; ++nt) sa[u][nt] = (f32x4){0.f, 0.f, 0.f, 0.f};
        __builtin_amdgcn_s_setprio(1);
        #pragma unroll
        for (int nt = 0; nt < 4; ++nt) {
            const int key = nt * 16 + c;
            bfrag kf[4];
            #pragma unroll
            for (int ks = 0; ks < 4; ++ks) {
                const int boff = (key * 256 + (ks * 32 + g * 8) * 2) ^ ((key & 7) << 4);
                kf[ks] = *(const bfrag*)(Ksm + boff);
            }
            #pragma unroll
            for (int u = 0; u < 2; ++u)
                #pragma unroll
                for (int ks = 0; ks < 4; ++ks)
                    sa[u][nt] = __builtin_amdgcn_mfma_f32_16x16x32_bf16(kf[ks], qf[u][ks], sa[u][nt], 0, 0, 0);
        }
        __builtin_amdgcn_s_setprio(0);

        // ---- lane-local softmax per q-group; pack P for both groups
        uint32_t pk0[2][4], pk1[2][4];
        #pragma unroll
        for (int u = 0; u < 2; ++u) {
            float mloc = sa[u][0][0];
            #pragma unroll
            for (int nt = 0; nt < 4; ++nt)
                #pragma unroll
                for (int r = 0; r < 4; ++r) mloc = fmaxf(mloc, sa[u][nt][r]);
            if (__any(mloc > mrun[u] + THR)) {
                float mt = mloc;
                mt = fmaxf(mt, __shfl_xor(mt, 16, 64));
                mt = fmaxf(mt, __shfl_xor(mt, 32, 64));
                const float mn = fmaxf(mrun[u], mt);
                const float fs = exp2f(mrun[u] - mn);
                mrun[u] = mn;
                lrun[u] *= fs;
                #pragma unroll
                for (int i = 0; i < 8; ++i) {
                    oacc[u][i][0] *= fs; oacc[u][i][1] *= fs;
                    oacc[u][i][2] *= fs; oacc[u][i][3] *= fs;
                }
            }
            float ps = 0.f;
            #pragma unroll
            for (int nt = 0; nt < 4; ++nt) {
                float p0 = exp2f(sa[u][nt][0] - mrun[u]);
                float p1 = exp2f(sa[u][nt][1] - mrun[u]);
                float p2 = exp2f(sa[u][nt][2] - mrun[u]);
                float p3 = exp2f(sa[u][nt][3] - mrun[u]);
                ps += (p0 + p1) + (p2 + p3);
                pk0[u][nt] = cvtpk(p0, p1);
                pk1[u][nt] = cvtpk(p2, p3);
            }
            ps += __shfl_xor(ps, 16, 64);
            ps += __shfl_xor(ps, 32, 64);
            lrun[u] += ps;
        }

        // ---- Oᵀ += V̂ᵀ · Pᵀ : V frags shared across both q-groups
        __builtin_amdgcn_s_setprio(1);
        #pragma unroll
        for (int k2 = 0; k2 < 2; ++k2) {
            union { uint32_t u[4]; bfrag f; } pb0, pb1;
            pb0.u[0] = pk0[0][2 * k2]; pb0.u[1] = pk1[0][2 * k2];
            pb0.u[2] = pk0[0][2 * k2 + 1]; pb0.u[3] = pk1[0][2 * k2 + 1];
            pb1.u[0] = pk0[1][2 * k2]; pb1.u[1] = pk1[1][2 * k2];
            pb1.u[2] = pk0[1][2 * k2 + 1]; pb1.u[3] = pk1[1][2 * k2 + 1];
            const int kb2 = (k2 * 32 + g * 8) * 2;
            #pragma unroll
            for (int mtl = 0; mtl < 8; ++mtl) {
                const int d = mtl * 16 + c;
                const bfrag va = *(const bfrag*)(Vsm + ((d * 128 + kb2) ^ ((d & 7) << 4)));
                oacc[0][mtl] = __builtin_amdgcn_mfma_f32_16x16x32_bf16(va, pb0.f, oacc[0][mtl], 0, 0, 0);
                oacc[1][mtl] = __builtin_amdgcn_mfma_f32_16x16x32_bf16(va, pb1.f, oacc[1][mtl], 0, 0, 0);
            }
        }
        __builtin_amdgcn_s_setprio(0);
    }

    // normalize
    #pragma unroll
    for (int u = 0; u < 2; ++u) {
        const float ic = 1.0f / lrun[u];
        #pragma unroll
        for (int i = 0; i < 8; ++i) {
            oacc[u][i][0] *= ic; oacc[u][i][1] *= ic;
            oacc[u][i][2] *= ic; oacc[u][i][3] *= ic;
        }
    }
    __syncthreads();   // done with K/V LDS; reuse as transpose scratch
    float* Ox = (float*)(smem + wv * 8192);   // per-wave [128 d][16 q]
    const int q = lane >> 2, qt = lane & 3;
    const int colbase = (qt >> 1) * 512 + hh * 64 + (qt & 1) * 32;
    #pragma unroll
    for (int u = 0; u < 2; ++u) {
        #pragma unroll
        for (int mtl = 0; mtl < 8; ++mtl)
            #pragma unroll
            for (int r = 0; r < 4; ++r)
                Ox[(mtl * 16 + 4 * g + r) * 16 + c] = oacc[u][mtl][r];
        asm volatile("s_waitcnt lgkmcnt(0)" ::: "memory");
        __builtin_amdgcn_sched_barrier(0);

        const size_t rowm = (size_t)bb * SEQ + q0 + wv * 32 + u * 16 + q;
        unsigned short* dst = Ah + rowm * KHAT + colbase;
        #pragma unroll
        for (int j = 0; j < 8; ++j) {
            us4 o;
            #pragma unroll
            for (int e = 0; e < 4; ++e) o[e] = f2bf(Ox[(qt * 32 + j * 4 + e) * 16 + q]);
            *(us4*)(dst + j * 4) = o;
        }
        asm volatile("s_waitcnt lgkmcnt(0)" ::: "memory");   // drain before next-u overwrite
        __builtin_amdgcn_sched_barrier(0);
    }
}

// ---------------------------------------------------------------- complex LayerNorm
//  bf16 residual stream: x = U(bf16) + Xh(bf16 residual); fp32 stats/whitening;
//  writes new Xh (bf16). LAST additionally writes fp32 d_out halves.
template <bool LAST>
__global__ __launch_bounds__(256)
void cln_kernel(const unsigned short* __restrict__ U,
                unsigned short* __restrict__ Xh,
                float* __restrict__ Outr, float* __restrict__ Outi,
                const float* __restrict__ Grr, const float* __restrict__ Gri,
                const float* __restrict__ Gii, const float* __restrict__ Bbr,
                const float* __restrict__ Bbi)
{
    const int lane = threadIdx.x & 63;
    const int row  = blockIdx.x * 4 + (threadIdx.x >> 6);
    const int c0 = lane * 4;
    const int c1 = 256 + lane * 4;

    float xr[8], xi[8];
    {
        const unsigned short* up = U  + (size_t)row * KHAT;
        const unsigned short* xp = Xh + (size_t)row * KHAT;
        us4 a0 = *(const us4*)(up + c0);
        us4 a1 = *(const us4*)(up + c1);
        us4 b0 = *(const us4*)(up + 512 + c0);
        us4 b1 = *(const us4*)(up + 512 + c1);
        us4 r0 = *(const us4*)(xp + c0);
        us4 r1 = *(const us4*)(xp + c1);
        us4 s0 = *(const us4*)(xp + 512 + c0);
        us4 s1 = *(const us4*)(xp + 512 + c1);
        #pragma unroll
        for (int j = 0; j < 4; ++j) {
            xr[j]     = bf2f(a0[j]) + bf2f(r0[j]);
            xr[4 + j] = bf2f(a1[j]) + bf2f(r1[j]);
            xi[j]     = bf2f(b0[j]) + bf2f(s0[j]);
            xi[4 + j] = bf2f(b1[j]) + bf2f(s1[j]);
        }
    }

    float sr = 0.f, si = 0.f, srr = 0.f, sii = 0.f, sri = 0.f;
    #pragma unroll
    for (int j = 0; j < 8; ++j) {
        sr += xr[j]; si += xi[j];
        srr = fmaf(xr[j], xr[j], srr);
        sii = fmaf(xi[j], xi[j], sii);
        sri = fmaf(xr[j], xi[j], sri);
    }
    #pragma unroll
    for (int m = 32; m >= 1; m >>= 1) {
        sr  += __shfl_xor(sr,  m, 64);
        si  += __shfl_xor(si,  m, 64);
        srr += __shfl_xor(srr, m, 64);
        sii += __shfl_xor(sii, m, 64);
        sri += __shfl_xor(sri, m, 64);
    }

    const float inv_d = 1.0f / DIM;
    const float mr = sr * inv_d, mi = si * inv_d;
    const float Vrr = srr * inv_d - mr * mr + 1e-5f;
    const float Vii = sii * inv_d - mi * mi + 1e-5f;
    const float Vri = sri * inv_d - mr * mi;
    const float s  = sqrtf(Vrr * Vii - Vri * Vri);
    const float tt = sqrtf(Vrr + Vii + 2.0f * s);
    const float ist = 1.0f / (s * tt);
    const float Wrr = (Vii + s) * ist;
    const float Wii = (Vrr + s) * ist;
    const float Wri = -Vri * ist;

    const size_t off = (size_t)row * DIM;
    #pragma unroll
    for (int half = 0; half < 2; ++half) {
        const int c = half ? c1 : c0;
        float grr[4], gri[4], gii[4], pbr[4], pbi[4];
        f4a(*(const float4*)&Grr[c], grr);
        f4a(*(const float4*)&Gri[c], gri);
        f4a(*(const float4*)&Gii[c], gii);
        f4a(*(const float4*)&Bbr[c], pbr);
        f4a(*(const float4*)&Bbi[c], pbi);
        float outr[4], outi[4];
        #pragma unroll
        for (int j = 0; j < 4; ++j) {
            const int idx = half * 4 + j;
            const float cr = xr[idx] - mr;
            const float ci = xi[idx] - mi;
            const float hr = Wrr * cr + Wri * ci;
            const float hi = Wri * cr + Wii * ci;
            outr[j] = fmaf(grr[j], hr, fmaf(gri[j], hi, pbr[j]));
            outi[j] = fmaf(gri[j], hr, fmaf(gii[j], hi, pbi[j]));
        }
        us4 hr_, hi_;
        #pragma unroll
        for (int j = 0; j < 4; ++j) { hr_[j] = f2bf(outr[j]); hi_[j] = f2bf(outi[j]); }
        *(us4*)(Xh + (size_t)row * KHAT + c)       = hr_;
        *(us4*)(Xh + (size_t)row * KHAT + 512 + c) = hi_;
        if (LAST) {
            *(float4*)&Outr[off + c] = a4f(outr);
            *(float4*)&Outi[off + c] = a4f(outi);
        }
    }
}

// ---------------------------------------------------------------- init: fp32 input -> bf16 X̂
__global__ __launch_bounds__(256)
void init_cvt(const float* __restrict__ xr, const float* __restrict__ xi,
              unsigned short* __restrict__ Xh)
{
    const size_t i = ((size_t)blockIdx.x * 256 + threadIdx.x) * 4;
    float vr[4], vi[4];
    f4a(*(const float4*)(xr + i), vr);
    f4a(*(const float4*)(xi + i), vi);
    const size_t m = i >> 9;
    const int k = (int)(i & 511);
    us4 a, b;
    #pragma unroll
    for (int j = 0; j < 4; ++j) { a[j] = f2bf(vr[j]); b[j] = f2bf(vi[j]); }
    *(us4*)(Xh + m * KHAT + k)       = a;
    *(us4*)(Xh + m * KHAT + 512 + k) = b;
}

// ---------------------------------------------------------------- host
extern "C" void kernel_launch(void* const* d_in, const int* in_sizes, int n_in,
                              void* d_out, int out_size, void* d_ws, size_t ws_size,
                              hipStream_t stream) {
    (void)in_sizes; (void)n_in; (void)out_size; (void)ws_size;

    const float* in_xr = (const float*)d_in[0];
    const float* in_xi = (const float*)d_in[1];
    PrepArgs pa;
    pa.Wr[0] = (const float*)d_in[2];  pa.Wi[0] = (const float*)d_in[3];   // q
    pa.Wr[1] = (const float*)d_in[4];  pa.Wi[1] = (const float*)d_in[5];   // k
    pa.Wr[2] = (const float*)d_in[6];  pa.Wi[2] = (const float*)d_in[7];   // v
    pa.Wr[3] = (const float*)d_in[8];  pa.Wi[3] = (const float*)d_in[9];   // o
    pa.Wr[4] = (const float*)d_in[10]; pa.Wi[4] = (const float*)d_in[11];  // f1
    pa.Wr[5] = (const float*)d_in[12]; pa.Wi[5] = (const float*)d_in[13];  // f2
    pa.br[0] = (const float*)d_in[14]; pa.bi[0] = (const float*)d_in[15];
    pa.br[1] = (const float*)d_in[16]; pa.bi[1] = (const float*)d_in[17];
    pa.br[2] = (const float*)d_in[18]; pa.bi[2] = (const float*)d_in[19];
    pa.br[3] = (const float*)d_in[20]; pa.bi[3] = (const float*)d_in[21];
    pa.br[4] = (const float*)d_in[22]; pa.bi[4] = (const float*)d_in[23];
    pa.br[5] = (const float*)d_in[24]; pa.bi[5] = (const float*)d_in[25];
    const float* ln1_grr = (const float*)d_in[26];
    const float* ln1_gii = (const float*)d_in[27];
    const float* ln2_grr = (const float*)d_in[28];
    const float* ln2_gii = (const float*)d_in[29];
    const float* ln1_gri = (const float*)d_in[30];
    const float* ln1_br  = (const float*)d_in[31];
    const float* ln1_bi  = (const float*)d_in[32];
    const float* ln2_gri = (const float*)d_in[33];
    const float* ln2_br  = (const float*)d_in[34];
    const float* ln2_bi  = (const float*)d_in[35];

    float* outr = (float*)d_out;
    float* outi = outr + BSD;

    char* ws = (char*)d_ws;
    unsigned short* Xh  = (unsigned short*)(ws);                    // 16 MiB each
    unsigned short* Qh  = (unsigned short*)(ws + 16777216);         // Q̂ / Ĥ (FFN hidden)
    unsigned short* Kh  = (unsigned short*)(ws + 2 * 16777216);     // K̂ / U (pre-LN bf16)
    unsigned short* Vth = (unsigned short*)(ws + 3 * 16777216);     // V̂t (κ-permuted keys)
    unsigned short* Ah  = (unsigned short*)(ws + 4 * 16777216);     // Â
    unsigned short* Ball = (unsigned short*)(ws + 5 * 16777216);    // 6 x 2 MiB
    float* biasall = (float*)(ws + 5 * 16777216 + 12582912);        // 24 KB
    unsigned short* Uh = Kh;
    unsigned short* Hh = Qh;

    init_cvt<<<ROWS * DIM / 1024, 256, 0, stream>>>(in_xr, in_xi, Xh);

    const dim3 pgrid(KHAT, 6);
    const dim3 qgrid(24, ROWS / 128);           // fused QKV: 1536 blocks
    const dim3 ggrid(KHAT / 128, ROWS / 128);   // (8, 64)
    const dim3 agrid(SEQ / 128, NH, NB);        // q-doubled: 512 blocks
    const int  lgrid = ROWS / 4;

    for (int l = 0; l < NL; ++l) {
        const size_t bo = (size_t)l * DIM;
        prep_kernel<<<pgrid, 256, 0, stream>>>(pa, Ball, biasall, l);

        unsigned short* Bo = Ball + (size_t)3 * KHAT * KHAT;
        unsigned short* B1 = Ball + (size_t)4 * KHAT * KHAT;
        unsigned short* B2 = Ball + (size_t)5 * KHAT * KHAT;

        gemm_qkv<<<qgrid, 256, 0, stream>>>(Xh, Ball, biasall, Qh, Kh, Vth);
        attn_mfma<<<agrid, 256, 0, stream>>>(Qh, Kh, Vth, Ah);
        gemm_mfma<false><<<ggrid, 256, 0, stream>>>(Ah, Bo, biasall + 3 * KHAT, Uh);
        cln_kernel<false><<<lgrid, 256, 0, stream>>>(Uh, Xh, nullptr, nullptr,
                                                     ln1_grr + bo, ln1_gri + bo, ln1_gii + bo,
                                                     ln1_br + bo, ln1_bi + bo);
        gemm_mfma<true><<<ggrid, 256, 0, stream>>>(Xh, B1, biasall + 4 * KHAT, Hh);
        gemm_mfma<false><<<ggrid, 256, 0, stream>>>(Hh, B2, biasall + 5 * KHAT, Uh);
        if (l == NL - 1) {
            cln_kernel<true><<<lgrid, 256, 0, stream>>>(Uh, Xh, outr, outi,
                                                        ln2_grr + bo, ln2_gri + bo, ln2_gii + bo,
                                                        ln2_br + bo, ln2_bi + bo);
        } else {
            cln_kernel<false><<<lgrid, 256, 0, stream>>>(Uh, Xh, nullptr, nullptr,
                                                         ln2_grr + bo, ln2_gri + bo, ln2_gii + bo,
                                                         ln2_br + bo, ln2_bi + bo);
        }
    }
}